// Round 10
// baseline (335.924 us; speedup 1.0000x reference)
//
#include <hip/hip_runtime.h>
#include <hip/hip_bf16.h>

using bf16 = __hip_bfloat16;
typedef __attribute__((ext_vector_type(8))) short bf16x8;
typedef __attribute__((ext_vector_type(4))) float f32x4;

// Shapes fixed: B=2, S=2048, D=1024, H=16, hd=64, F=2048.
// BOTH batches processed concurrently where scratch allows.
// 8 slots of 4MB (M2 = 2M bf16 elems): r0..r3 (ws), P0a/P0b (=pb0),
// P1a/P1b (=pb1). Slot lifetimes audited per dispatch (see r9 header).
// This round: attn QBLK=128 (2x work per K-tile amortizes staging/barriers;
// K/V frag reads shared across the two q-halves); W3T(b0) merged into
// prep2(b0)'s grid.

__device__ inline float toF(float x) { return x; }
__device__ inline float toF(bf16 x) { return __bfloat162float(x); }

__device__ __forceinline__ void unpack8(uint4 u, float* f) {
    f[0] = __uint_as_float(u.x << 16); f[1] = __uint_as_float(u.x & 0xffff0000u);
    f[2] = __uint_as_float(u.y << 16); f[3] = __uint_as_float(u.y & 0xffff0000u);
    f[4] = __uint_as_float(u.z << 16); f[5] = __uint_as_float(u.z & 0xffff0000u);
    f[6] = __uint_as_float(u.w << 16); f[7] = __uint_as_float(u.w & 0xffff0000u);
}

__device__ __forceinline__ uint4 packbf8(const float* f) {
    union { unsigned short u[8]; uint4 v; } r;
#pragma unroll
    for (int i = 0; i < 8; i++) {
        bf16 b = __float2bfloat16(f[i]);
        r.u[i] = *(unsigned short*)&b;
    }
    return r.v;
}

__device__ __forceinline__ unsigned pack2(float lo, float hi) {
    bf16 a = __float2bfloat16(lo), b = __float2bfloat16(hi);
    return ((unsigned)*(unsigned short*)&b << 16) | (unsigned)*(unsigned short*)&a;
}

__device__ __forceinline__ void gl_lds16(const void* g, void* l) {
    __builtin_amdgcn_global_load_lds(
        (__attribute__((address_space(1))) void*)g,
        (__attribute__((address_space(3))) void*)l, 16, 0, 0);
}

// ---------------------------------------------------------------------------
// LN body: one block per row, D=1024, 256 threads.
// ---------------------------------------------------------------------------
template <typename Tx>
__device__ __forceinline__ void ln_body(
    const Tx* __restrict__ x, const float* __restrict__ g,
    const float* __restrict__ b, bf16* __restrict__ out, int row,
    float* s1, float* s2)
{
    const int D = 1024;
    int tid = threadIdx.x;
    const Tx* xr = x + (size_t)row * D;

    float vals[4];
    float sum = 0.f, sumsq = 0.f;
#pragma unroll
    for (int i = 0; i < 4; i++) {
        float v = toF(xr[tid + i * 256]);
        vals[i] = v; sum += v; sumsq += v * v;
    }
#pragma unroll
    for (int off = 32; off > 0; off >>= 1) {
        sum += __shfl_xor(sum, off);
        sumsq += __shfl_xor(sumsq, off);
    }
    int wave = tid >> 6, lane = tid & 63;
    if (lane == 0) { s1[wave] = sum; s2[wave] = sumsq; }
    __syncthreads();
    sum = s1[0] + s1[1] + s1[2] + s1[3];
    sumsq = s2[0] + s2[1] + s2[2] + s2[3];

    float mu = sum * (1.f / D);
    float var = sumsq * (1.f / D) - mu * mu;
    float rstd = rsqrtf(var + 1e-5f);

    bf16* orow = out + (size_t)row * D;
#pragma unroll
    for (int i = 0; i < 4; i++) {
        int c = tid + i * 256;
        orow[c] = __float2bfloat16((vals[i] - mu) * rstd * g[c] + b[c]);
    }
}

// ---------------------------------------------------------------------------
// prep1F: blocks [0,4096): LN1 rows, both batches (b = bx>>11)
//         blocks [4096,7168): WqT/WkT/WvT transpose (48 z-slices)
// ---------------------------------------------------------------------------
__global__ __launch_bounds__(256) void prep1_kernel(
    const float* __restrict__ x, const float* __restrict__ g,
    const float* __restrict__ b, bf16* __restrict__ h0, bf16* __restrict__ h1,
    const float* __restrict__ Wq, const float* __restrict__ Wk,
    const float* __restrict__ Wv, bf16* __restrict__ wt)
{
    __shared__ float t[32][33];
    __shared__ float s1[4], s2[4];
    int bx = blockIdx.x;
    if (bx < 4096) {
        int bb = bx >> 11, row = bx & 2047;
        ln_body<float>(x + ((size_t)bb << 21), g, b, bb ? h1 : h0, row, s1, s2);
        return;
    }
    int zz = bx - 4096;
    int z = zz >> 6, rem = zz & 63;
    int yy = rem >> 1, xx = rem & 1;
    const float* s = (z < 16) ? Wq : (z < 32) ? Wk : Wv;
    const float* ip = s + (size_t)(z & 15) * 65536;
    bf16* op = wt + ((size_t)z << 16);
    int c0 = xx * 32, r0 = yy * 32;
    int tx = threadIdx.x & 31, ty = threadIdx.x >> 5;
#pragma unroll
    for (int i = 0; i < 4; i++)
        t[ty + 8 * i][tx] = ip[(size_t)(r0 + ty + 8 * i) * 64 + c0 + tx];
    __syncthreads();
#pragma unroll
    for (int i = 0; i < 4; i++)
        op[(size_t)(c0 + ty + 8 * i) * 1024 + r0 + tx] = __float2bfloat16(t[tx][ty + 8 * i]);
}

// ---------------------------------------------------------------------------
// prep2: blocks [0,2048): LN2 row (bf16 x2 -> bf16 h2)
//        blocks [2048,6144): W1T/W2T transpose ([1024][2048] -> [2048][1024])
//        blocks [6144,8192): W3T transpose ([2048][1024] -> [1024][2048])
//        (W3T section only dispatched for batch-0's grid of 8192)
// ---------------------------------------------------------------------------
__global__ __launch_bounds__(256) void prep2_kernel(
    const bf16* __restrict__ x2, const float* __restrict__ g,
    const float* __restrict__ b, bf16* __restrict__ h2,
    const float* __restrict__ W1, const float* __restrict__ W2,
    bf16* __restrict__ wt, const float* __restrict__ W3,
    bf16* __restrict__ w3t)
{
    __shared__ float t[32][33];
    __shared__ float s1[4], s2[4];
    int bx = blockIdx.x;
    if (bx < 2048) {
        ln_body<bf16>(x2, g, b, h2, bx, s1, s2);
        return;
    }
    int tx = threadIdx.x & 31, ty = threadIdx.x >> 5;
    int zz = bx - 2048;
    if (zz < 4096) {
        int xx = zz & 63, yy = (zz >> 6) & 31, z = zz >> 11;
        const float* ip = z ? W2 : W1;
        bf16* op = wt + ((size_t)z << 21);
        int c0 = xx * 32, r0 = yy * 32;
#pragma unroll
        for (int i = 0; i < 4; i++)
            t[ty + 8 * i][tx] = ip[(size_t)(r0 + ty + 8 * i) * 2048 + c0 + tx];
        __syncthreads();
#pragma unroll
        for (int i = 0; i < 4; i++)
            op[(size_t)(c0 + ty + 8 * i) * 1024 + r0 + tx] = __float2bfloat16(t[tx][ty + 8 * i]);
        return;
    }
    // W3T: [2048][1024] fp32 -> [1024][2048] bf16
    int idx = zz - 4096;
    int xx = idx & 31, yy = idx >> 5;
    int c0 = xx * 32, r0 = yy * 32;
#pragma unroll
    for (int i = 0; i < 4; i++)
        t[ty + 8 * i][tx] = W3[(size_t)(r0 + ty + 8 * i) * 1024 + c0 + tx];
    __syncthreads();
#pragma unroll
    for (int i = 0; i < 4; i++)
        w3t[(size_t)(c0 + ty + 8 * i) * 2048 + r0 + tx] = __float2bfloat16(t[tx][ty + 8 * i]);
}

// ---------------------------------------------------------------------------
// Generic transpose+convert (W3 for batch 1): fp32 [R][C] -> bf16 [C][R].
// ---------------------------------------------------------------------------
__global__ __launch_bounds__(256) void tconv_kernel(
    const float* __restrict__ in, bf16* __restrict__ out, int R, int C)
{
    __shared__ float t[32][33];
    int c0 = blockIdx.x * 32, r0 = blockIdx.y * 32;
    int tx = threadIdx.x & 31, ty = threadIdx.x >> 5;
#pragma unroll
    for (int i = 0; i < 4; i++)
        t[ty + 8 * i][tx] = in[(size_t)(r0 + ty + 8 * i) * C + c0 + tx];
    __syncthreads();
#pragma unroll
    for (int i = 0; i < 4; i++)
        out[(size_t)(c0 + ty + 8 * i) * R + r0 + tx] = __float2bfloat16(t[tx][ty + 8 * i]);
}

// Wo transpose: 16 64-col slices of [1024][1024] -> [64][1024] each.
__global__ __launch_bounds__(256) void tconv_wo_kernel(
    const float* __restrict__ Wo, bf16* __restrict__ out)
{
    __shared__ float t[32][33];
    int z = blockIdx.z;
    const float* ip = Wo + (size_t)z * 64;
    bf16* op = out + ((size_t)z << 16);
    int c0 = blockIdx.x * 32, r0 = blockIdx.y * 32;
    int tx = threadIdx.x & 31, ty = threadIdx.x >> 5;
#pragma unroll
    for (int i = 0; i < 4; i++)
        t[ty + 8 * i][tx] = ip[(size_t)(r0 + ty + 8 * i) * 1024 + c0 + tx];
    __syncthreads();
#pragma unroll
    for (int i = 0; i < 4; i++)
        op[(size_t)(c0 + ty + 8 * i) * 1024 + r0 + tx] = __float2bfloat16(t[tx][ty + 8 * i]);
}

// ---------------------------------------------------------------------------
// MFMA GEMM: C[M,N] = A[M,K](bf16) @ B (BT[N,K] bf16), fp32 accum.
// 64x64 tile, BK=64 double-buffer, 4 waves (2x2), wave tile 32x32.
// Source-pre-swizzled LDS (conflict-free ds_read_b128), setprio around MFMA.
//
// MODE 1 (QKF): z=0..3: bit1=batch (A=A / resv; C=Cv / p6), bit0=q/k
//         (BT0 + bit0*1M; C + bit0*2M). Scatter [H][S][64] + RoPE always.
// MODE 6 (V^T): C written directly as vt[h][d][s] (packed uint2).
// MODE 2 (F):  z=batch: A=A/p5, res=resv fp32 +z*2M, C=Cv/p6; C bf16=acc+res.
// MODE 4: C f32 = acc + resBf16
// MODE 5: fused SwiGLU dual-B (B1=BT0, B2=resv); C bf16 = silu(u)*g. 48KB LDS.
// ---------------------------------------------------------------------------
template <int MODE>
__global__ __launch_bounds__(256) void mfma_gemm(
    const bf16* __restrict__ A, const bf16* __restrict__ BT0,
    void* __restrict__ Cv, const void* __restrict__ resv,
    const void* __restrict__ p5, void* __restrict__ p6,
    int M, int N, int K)
{
    constexpr int NB = (MODE == 5) ? 3 : 2;            // matrices per buffer
    __shared__ bf16 smem[2][NB][64 * 64];              // 32KB / 48KB
    int tid = threadIdx.x, lane = tid & 63, w = tid >> 6;
    int wm = w >> 1, wn = w & 1;
    int m0 = blockIdx.y * 64, n0 = blockIdx.x * 64;

    const bf16* Ap = A;
    const bf16* BT = BT0;
    bf16* Cq = nullptr;
    const float* resF = (const float*)resv;
    void* Cdst = Cv;
    if (MODE == 1) {
        int z = blockIdx.z;
        if (z >> 1) Ap = (const bf16*)resv;            // h1
        BT = BT0 + ((size_t)(z & 1) << 20);
        Cq = (bf16*)((z >> 1) ? p6 : Cv) + ((size_t)(z & 1) << 21);
    }
    if (MODE == 6) Cq = (bf16*)Cv;
    if (MODE == 2) {
        int z = blockIdx.z;
        if (z) { Ap = (const bf16*)p5; Cdst = p6; }
        resF = (const float*)resv + ((size_t)z << 21);
    }

    int lrow = lane >> 3;                  // 0..7
    int lcb  = (lane & 7) ^ lrow;          // pre-swizzled 16B col-block
    const bf16* Ag  = Ap + (size_t)(m0 + w * 8 + lrow) * K + lcb * 8;
    const bf16* Bg0 = BT + (size_t)(n0 + w * 8 + lrow) * K + lcb * 8;
    const bf16* B2g = (MODE == 5)
        ? (const bf16*)resv + (size_t)(n0 + w * 8 + lrow) * K + lcb * 8
        : nullptr;
    unsigned sbase = (unsigned)__builtin_amdgcn_readfirstlane(w * 8 * 128);
    char* smc = (char*)smem;

    f32x4 acc[2][2], acc2[2][2];
#pragma unroll
    for (int i = 0; i < 2; i++)
#pragma unroll
        for (int j = 0; j < 2; j++) {
            acc[i][j] = (f32x4){0.f, 0.f, 0.f, 0.f};
            if (MODE == 5) acc2[i][j] = (f32x4){0.f, 0.f, 0.f, 0.f};
        }

    int cidx = lane & 15, quad = lane >> 4;

    auto STAGE = [&](int buf, int k0) {
        char* p = smc + (size_t)buf * (NB * 8192) + sbase;
        gl_lds16(Ag + k0,                   p);
        gl_lds16(Ag + (size_t)32 * K + k0,  p + 4096);
        gl_lds16(Bg0 + k0,                  p + 8192);
        gl_lds16(Bg0 + (size_t)32 * K + k0, p + 12288);
        if (MODE == 5) {
            gl_lds16(B2g + k0,                  p + 16384);
            gl_lds16(B2g + (size_t)32 * K + k0, p + 20480);
        }
    };

    STAGE(0, 0);
    __syncthreads();                 // drains vmcnt, publishes buf0
    int cur = 0;
    for (int k0 = 0; k0 < K; k0 += 64) {
        if (k0 + 64 < K) STAGE(cur ^ 1, k0 + 64);   // prefetch next
        const bf16* Ab = (const bf16*)(smc + (size_t)cur * (NB * 8192));
        const bf16* Bb = Ab + 4096;
        const bf16* B2b = Ab + 8192;
#pragma unroll
        for (int kk = 0; kk < 2; kk++) {
            int pb = (kk * 4 + quad) ^ (cidx & 7);  // swizzled slot
            bf16x8 af[2], bfr[2], b2f[2];
#pragma unroll
            for (int i = 0; i < 2; i++)
                af[i] = *(const bf16x8*)&Ab[(wm * 32 + i * 16 + cidx) * 64 + pb * 8];
#pragma unroll
            for (int j = 0; j < 2; j++)
                bfr[j] = *(const bf16x8*)&Bb[(wn * 32 + j * 16 + cidx) * 64 + pb * 8];
            if (MODE == 5) {
#pragma unroll
                for (int j = 0; j < 2; j++)
                    b2f[j] = *(const bf16x8*)&B2b[(wn * 32 + j * 16 + cidx) * 64 + pb * 8];
            }
            __builtin_amdgcn_s_setprio(1);
#pragma unroll
            for (int i = 0; i < 2; i++)
#pragma unroll
                for (int j = 0; j < 2; j++) {
                    acc[i][j] = __builtin_amdgcn_mfma_f32_16x16x32_bf16(af[i], bfr[j], acc[i][j], 0, 0, 0);
                    if (MODE == 5)
                        acc2[i][j] = __builtin_amdgcn_mfma_f32_16x16x32_bf16(af[i], b2f[j], acc2[i][j], 0, 0, 0);
                }
            __builtin_amdgcn_s_setprio(0);
        }
        __syncthreads();             // reads of cur done + prefetch landed
        cur ^= 1;
    }

    int rbase = quad * 4;
#pragma unroll
    for (int i = 0; i < 2; i++) {
#pragma unroll
        for (int j = 0; j < 2; j++) {
            int row0 = m0 + wm * 32 + i * 16 + rbase;
            int col = n0 + wn * 32 + j * 16 + cidx;
            if (MODE == 6) {
                // direct V^T write vt[h][d][s], 4 consecutive s packed
                int h_ = col >> 6, d = col & 63;
                uint2 t;
                t.x = pack2(acc[i][j][0], acc[i][j][1]);
                t.y = pack2(acc[i][j][2], acc[i][j][3]);
                *(uint2*)&Cq[(size_t)h_ * 131072 + (size_t)d * 2048 + row0] = t;
                continue;
            }
#pragma unroll
            for (int r = 0; r < 4; r++) {
                int row = row0 + r;
                float v = acc[i][j][r];
                size_t idx = (size_t)row * N + col;
                if (MODE == 1) {
                    int h_ = col >> 6, kk = col & 63;
                    float other = __shfl_xor(v, 1);
                    float p = (float)(kk >> 1);
                    float theta = __expf(p * -0.5756462732485114f); // ln(1e4)/16
                    float ang = (float)row * theta;
                    float c, sn; __sincosf(ang, &sn, &c);
                    float outv = (kk & 1) ? (v * c + other * sn) : (v * c - other * sn);
                    Cq[((size_t)h_ * 2048 + row) * 64 + kk] = __float2bfloat16(outv);
                } else if (MODE == 2) {
                    v += resF[idx];
                    ((bf16*)Cdst)[idx] = __float2bfloat16(v);
                } else if (MODE == 5) {
                    float g2 = acc2[i][j][r];
                    float sg = 1.f / (1.f + __expf(-v));
                    ((bf16*)Cv)[idx] = __float2bfloat16(v * sg * g2);
                } else {
                    v += __bfloat162float(((const bf16*)resv)[idx]);
                    ((float*)Cv)[idx] = v;
                }
            }
        }
    }
}

// ---------------------------------------------------------------------------
// MFMA causal flash attention, BOTH batches (z = batch). hd=64.
// QBLK=128 (this round), KVBLK=64. Each wave owns 32 q-rows = two 16-row
// halves; K/V A-frags are loaded once per subtile and shared across halves.
// Per-half online softmax (log2 domain, deferred-l, defer-max THR=8).
// Grid (16,16,2) = 512 blocks; qt = z ? bx : 15-bx pairs heavy+light on
// each CU (pair iteration sum = 34 everywhere).
// Reg budget ~130 VGPR, capped via __launch_bounds__(256,2) -> no spill.
// LDS: Ks 8K + Vs 8K + QP 18K = 34KB.
// ---------------------------------------------------------------------------
__global__ __launch_bounds__(256, 2) void attn_kernel(
    const bf16* __restrict__ q0, const bf16* __restrict__ k0,
    const bf16* __restrict__ vt0, bf16* __restrict__ o0,
    const bf16* __restrict__ q1, const bf16* __restrict__ k1,
    const bf16* __restrict__ vt1, bf16* __restrict__ o1)
{
    const int S = 2048;
    __shared__ bf16 Ks[64 * 64];
    __shared__ bf16 Vs[64 * 64];
    __shared__ __align__(16) char QPbuf[128 * 72 * 2];   // 18432B: Q stage / P strips

    int zb = blockIdx.z;
    const bf16* q = zb ? q1 : q0;
    const bf16* k = zb ? k1 : k0;
    const bf16* vt = zb ? vt1 : vt0;
    bf16* o = zb ? o1 : o0;

    int h = blockIdx.y;
    int qt = zb ? (int)blockIdx.x : 15 - (int)blockIdx.x;
    int tid = threadIdx.x, lane = tid & 63, w = tid >> 6;
    int quad = lane >> 4, cidx = lane & 15;
    int m0 = qt * 128;

    const bf16* qb = q + ((size_t)h * S + m0) * 64;
    const bf16* kb = k + (size_t)h * S * 64;
    const bf16* vtb = vt + (size_t)h * 64 * S;

    int srow = tid >> 2;          // 0..63 (K/V staging row)
    int sg = (tid & 3) * 16;

    // ---- stage Q (128 rows) * (0.125*log2e); wave w stages rows w*32..+31
    bf16 (*Qs)[72] = (bf16 (*)[72])QPbuf;
    {
        int srow2 = tid >> 1, sg2 = (tid & 1) * 32;
        const uint4* src = (const uint4*)(qb + (size_t)srow2 * 64 + sg2);
#pragma unroll
        for (int p = 0; p < 2; p++) {
            uint4 u0 = src[2 * p], u1 = src[2 * p + 1];
            float f[16]; unpack8(u0, f); unpack8(u1, f + 8);
#pragma unroll
            for (int i = 0; i < 16; i++) f[i] *= 0.125f * 1.44269504f;
            *(uint4*)&Qs[srow2][sg2 + 16 * p] = packbf8(f);
            *(uint4*)&Qs[srow2][sg2 + 16 * p + 8] = packbf8(f + 8);
        }
    }
    // same-wave LDS write->read (wave-private rows); no barrier needed
    bf16x8 bQ[2][2];
#pragma unroll
    for (int hf = 0; hf < 2; hf++) {
        bQ[hf][0] = *(const bf16x8*)&Qs[w * 32 + hf * 16 + cidx][quad * 8];
        bQ[hf][1] = *(const bf16x8*)&Qs[w * 32 + hf * 16 + cidx][32 + quad * 8];
    }

    unsigned* Pst = (unsigned*)QPbuf + w * (32 * 36);   // 32-row strip per wave

    int cb0 = (tid & 3) * 2;
    int sw0 = ((cb0)     ^ (srow & 7)) * 8;
    int sw1 = ((cb0 + 1) ^ (srow & 7)) * 8;
    int pb0 = ((quad)     ^ (cidx & 7)) * 8;
    int pb1 = ((4 + quad) ^ (cidx & 7)) * 8;

    float m_i[2] = {-INFINITY, -INFINITY};
    float l_i[2] = {0.f, 0.f};               // per-lane PARTIAL sums
    f32x4 Oc[2][4];
#pragma unroll
    for (int hf = 0; hf < 2; hf++)
#pragma unroll
        for (int i = 0; i < 4; i++) Oc[hf][i] = (f32x4){0.f, 0.f, 0.f, 0.f};

    int nt = 2 * qt + 2;          // 64-row K tiles covering [0, m0+128)

    uint4 ka0, ka1, va0, va1;
    {
        const uint4* ksrc = (const uint4*)(kb + (size_t)srow * 64 + sg);
        ka0 = ksrc[0]; ka1 = ksrc[1];
        const uint4* vsrc = (const uint4*)(vtb + (size_t)srow * S + sg);
        va0 = vsrc[0]; va1 = vsrc[1];
    }

    for (int kt = 0; kt < nt; kt++) {
        __syncthreads();
        *(uint4*)&Ks[srow * 64 + sw0] = ka0;
        *(uint4*)&Ks[srow * 64 + sw1] = ka1;
        *(uint4*)&Vs[srow * 64 + sw0] = va0;
        *(uint4*)&Vs[srow * 64 + sw1] = va1;
        __syncthreads();
        if (kt + 1 < nt) {
            const uint4* kn = (const uint4*)(kb + (size_t)((kt + 1) * 64 + srow) * 64 + sg);
            ka0 = kn[0]; ka1 = kn[1];
            const uint4* vn = (const uint4*)(vtb + (size_t)srow * S + (kt + 1) * 64 + sg);
            va0 = vn[0]; va1 = vn[1];
        }

        // S^T: sc[hf][i] = S^T[kpos=kt*64+i*16+quad*4+r][q=w*32+hf*16+cidx]
        f32x4 sc[2][4];
#pragma unroll
        for (int i = 0; i < 4; i++) {
            bf16x8 aK0 = *(const bf16x8*)&Ks[(i * 16 + cidx) * 64 + pb0];
            bf16x8 aK1 = *(const bf16x8*)&Ks[(i * 16 + cidx) * 64 + pb1];
            __builtin_amdgcn_s_setprio(1);
#pragma unroll
            for (int hf = 0; hf < 2; hf++) {
                f32x4 z = (f32x4){0.f, 0.f, 0.f, 0.f};
                z = __builtin_amdgcn_mfma_f32_16x16x32_bf16(aK0, bQ[hf][0], z, 0, 0, 0);
                z = __builtin_amdgcn_mfma_f32_16x16x32_bf16(aK1, bQ[hf][1], z, 0, 0, 0);
                sc[hf][i] = z;
            }
            __builtin_amdgcn_s_setprio(0);
        }

        if (kt >= nt - 2) {       // causal mask only possible on last 2 tiles
#pragma unroll
            for (int hf = 0; hf < 2; hf++) {
                int qpos = m0 + w * 32 + hf * 16 + cidx;
#pragma unroll
                for (int i = 0; i < 4; i++)
#pragma unroll
                    for (int r = 0; r < 4; r++)
                        if (kt * 64 + i * 16 + quad * 4 + r > qpos)
                            sc[hf][i][r] = -INFINITY;
            }
        }

#pragma unroll
        for (int hf = 0; hf < 2; hf++) {
            float l0 = fmaxf(fmaxf(sc[hf][0][0], sc[hf][0][1]), fmaxf(sc[hf][0][2], sc[hf][0][3]));
            float l1 = fmaxf(fmaxf(sc[hf][1][0], sc[hf][1][1]), fmaxf(sc[hf][1][2], sc[hf][1][3]));
            float l2 = fmaxf(fmaxf(sc[hf][2][0], sc[hf][2][1]), fmaxf(sc[hf][2][2], sc[hf][2][3]));
            float l3 = fmaxf(fmaxf(sc[hf][3][0], sc[hf][3][1]), fmaxf(sc[hf][3][2], sc[hf][3][3]));
            float lmax = fmaxf(fmaxf(l0, l1), fmaxf(l2, l3));

            if (!__all(lmax <= m_i[hf] + 8.f)) {
                float pmax = fmaxf(lmax, __shfl_xor(lmax, 16));
                pmax = fmaxf(pmax, __shfl_xor(pmax, 32));
                float mnew = fmaxf(m_i[hf], pmax);
                float alpha = __builtin_amdgcn_exp2f(m_i[hf] - mnew);
                l_i[hf] *= alpha;
#pragma unroll
                for (int i = 0; i < 4; i++) {
                    Oc[hf][i][0] *= alpha; Oc[hf][i][1] *= alpha;
                    Oc[hf][i][2] *= alpha; Oc[hf][i][3] *= alpha;
                }
                m_i[hf] = mnew;
            }

            float rs = 0.f;
#pragma unroll
            for (int i = 0; i < 4; i++)
#pragma unroll
                for (int r = 0; r < 4; r++) {
                    sc[hf][i][r] = __builtin_amdgcn_exp2f(sc[hf][i][r] - m_i[hf]);
                    rs += sc[hf][i][r];
                }
            l_i[hf] += rs;

            // P^T -> strip row (hf*16+cidx); b64 packed writes
#pragma unroll
            for (int i = 0; i < 4; i++) {
                uint2 t;
                t.x = pack2(sc[hf][i][0], sc[hf][i][1]);
                t.y = pack2(sc[hf][i][2], sc[hf][i][3]);
                *(uint2*)&Pst[(hf * 16 + cidx) * 36 + 8 * i + 2 * quad] = t;
            }
        }

        bf16x8 bP[2][2];
#pragma unroll
        for (int hf = 0; hf < 2; hf++) {
            bP[hf][0] = *(const bf16x8*)&Pst[(hf * 16 + cidx) * 36 + 4 * quad];
            bP[hf][1] = *(const bf16x8*)&Pst[(hf * 16 + cidx) * 36 + 16 + 4 * quad];
        }

        // O^T += V^T * P^T (A-frags shared across halves)
#pragma unroll
        for (int i = 0; i < 4; i++) {
            bf16x8 aV0 = *(const bf16x8*)&Vs[(i * 16 + cidx) * 64 + pb0];
            bf16x8 aV1 = *(const bf16x8*)&Vs[(i * 16 + cidx) * 64 + pb1];
            __builtin_amdgcn_s_setprio(1);
#pragma unroll
            for (int hf = 0; hf < 2; hf++) {
                Oc[hf][i] = __builtin_amdgcn_mfma_f32_16x16x32_bf16(aV0, bP[hf][0], Oc[hf][i], 0, 0, 0);
                Oc[hf][i] = __builtin_amdgcn_mfma_f32_16x16x32_bf16(aV1, bP[hf][1], Oc[hf][i], 0, 0, 0);
            }
            __builtin_amdgcn_s_setprio(0);
        }
    }

    // epilogue per half: reduce l (deferred), normalize, strip-transpose, store
    int r2 = lane >> 2, g2 = (lane & 3) * 8;
#pragma unroll
    for (int hf = 0; hf < 2; hf++) {
        float lr = l_i[hf];
        lr += __shfl_xor(lr, 16);
        lr += __shfl_xor(lr, 32);
        float inv = 1.f / lr;
#pragma unroll
        for (int i = 0; i < 4; i++) {
            uint2 t;
            t.x = pack2(Oc[hf][i][0] * inv, Oc[hf][i][1] * inv);
            t.y = pack2(Oc[hf][i][2] * inv, Oc[hf][i][3] * inv);
            *(uint2*)&Pst[(hf * 16 + cidx) * 36 + 8 * i + 2 * quad] = t;
        }
        uint4 o0v = *(const uint4*)&Pst[(hf * 16 + r2) * 36 + g2];
        uint4 o1v = *(const uint4*)&Pst[(hf * 16 + r2) * 36 + g2 + 4];
        bf16* orow = o + (size_t)(m0 + w * 32 + hf * 16 + r2) * 1024 + h * 64;
        *(uint4*)(orow + g2 * 2) = o0v;
        *(uint4*)(orow + g2 * 2 + 8) = o1v;
    }
}

// ---------------------------------------------------------------------------
extern "C" void kernel_launch(void* const* d_in, const int* in_sizes, int n_in,
                              void* d_out, int out_size, void* d_ws, size_t ws_size,
                              hipStream_t stream)
{
    const int S = 2048;

    const float* x    = (const float*)d_in[0];
    const float* ln1g = (const float*)d_in[1];
    const float* ln1b = (const float*)d_in[2];
    const float* Wq   = (const float*)d_in[3];
    const float* Wk   = (const float*)d_in[4];
    const float* Wv   = (const float*)d_in[5];
    const float* Wo   = (const float*)d_in[6];
    const float* ln2g = (const float*)d_in[7];
    const float* ln2b = (const float*)d_in[8];
    const float* W1   = (const float*)d_in[9];
    const float* W2   = (const float*)d_in[10];
    const float* W3   = (const float*)d_in[11];
    float* out = (float*)d_out;

    const size_t M2 = 1u << 21;        // 2M bf16 elems (one 4MB slot)
    bf16* r0 = (bf16*)d_ws;
    bf16* r1 = r0 + M2;
    bf16* r2 = r1 + M2;
    bf16* r3 = r2 + M2;
    bf16* pb0 = (bf16*)out;            // P0a = pb0, P0b = pb0+M2
    bf16* pb1 = pb0 + 2 * M2;          // P1a = pb1, P1b = pb1+M2
    float* out0 = out;
    float* out1 = out + (1u << 21);    // batch-1 output (2M floats offset)

    // 1. LN1 both -> r0,r1; WqT/WkT/WvT -> pb0[0:3M elems)
    prep1_kernel<<<7168, 256, 0, stream>>>(x, ln1g, ln1b, r0, r1,
                                           Wq, Wk, Wv, pb0);

    // 2. QKF: q0->r2, k0->r3, q1->P1a, k1->P1b (RoPE all)
    mfma_gemm<1><<<dim3(16, 32, 4), 256, 0, stream>>>(
        r0, pb0, r2, r1, nullptr, pb1, S, 1024, 1024);

    // 3. vt0 = (h0 @ Wv)^T -> pb0[0:M2)  (WvT at pb0+M2; WqT/WkT dead)
    mfma_gemm<6><<<dim3(16, 32, 1), 256, 0, stream>>>(
        r0, pb0 + M2, pb0, nullptr, nullptr, nullptr, S, 1024, 1024);

    // 4. vt1 -> r0 (h0 dead)
    mfma_gemm<6><<<dim3(16, 32, 1), 256, 0, stream>>>(
        r1, pb0 + M2, r0, nullptr, nullptr, nullptr, S, 1024, 1024);

    // 5. attnF: ao0 -> r1 (h1 dead), ao1 -> pb0+M2 (WvT dead)
    attn_kernel<<<dim3(16, 16, 2), 256, 0, stream>>>(
        r2, r3, pb0, r1, pb1, pb1 + M2, r0, pb0 + M2);

    // 6a. WoT -> r2 (q0 dead)
    tconv_wo_kernel<<<dim3(2, 32, 16), 256, 0, stream>>>(Wo, r2);

    // 6b. mode2F: x2_0 = x0 + ao0@Wo -> r3 (k0 dead); x2_1 -> r0 (vt1 dead)
    mfma_gemm<2><<<dim3(16, 32, 2), 256, 0, stream>>>(
        r1, r2, r3, x, pb0 + M2, r0, S, 1024, 1024);

    // 7a. prep2(b0)+W3T: h2_0 -> P1a (q1 dead); W1T->pb0, W2T->pb0+M2;
    //     W3T -> P1b (k1 dead)
    prep2_kernel<<<8192, 256, 0, stream>>>(r3, ln2g, ln2b, pb1, W1, W2, pb0,
                                           W3, pb1 + M2);

    // 7b. mode5(b0): sb0 = silu(h2_0@W1)*(h2_0@W2) -> r1..r2
    mfma_gemm<5><<<dim3(32, 32, 1), 256, 0, stream>>>(
        pb1, pb0, r1, pb0 + M2, nullptr, nullptr, S, 2048, 1024);

    // 7d. out0 = x2_0 + sb0@W3 -> pb0 fp32 (W12T dead)
    mfma_gemm<4><<<dim3(16, 32, 1), 256, 0, stream>>>(
        r1, pb1 + M2, out0, r3, nullptr, nullptr, S, 1024, 2048);

    // 8a. prep2(b1): x2_1=r0 -> h2_1 -> r3 (x2_0 dead); W12T -> pb1
    prep2_kernel<<<6144, 256, 0, stream>>>(r0, ln2g, ln2b, r3, W1, W2, pb1,
                                           nullptr, nullptr);

    // 8b. mode5(b1): sb1 -> r1..r2 (sb0 dead)
    mfma_gemm<5><<<dim3(32, 32, 1), 256, 0, stream>>>(
        r3, pb1, r1, pb1 + M2, nullptr, nullptr, S, 2048, 1024);

    // 8c. W3T -> r3 (h2_1 dead)
    tconv_kernel<<<dim3(32, 64), 256, 0, stream>>>(W3, r3, 2048, 1024);

    // 8d. out1 = x2_1 + sb1@W3 -> pb1 fp32 (W12T dead)
    mfma_gemm<4><<<dim3(16, 32, 1), 256, 0, stream>>>(
        r1, r3, out1, r0, nullptr, nullptr, S, 1024, 2048);
}

// Round 11
// 332.931 us; speedup vs baseline: 1.0090x; 1.0090x over previous
//
#include <hip/hip_runtime.h>
#include <hip/hip_bf16.h>

using bf16 = __hip_bfloat16;
typedef __attribute__((ext_vector_type(8))) short bf16x8;
typedef __attribute__((ext_vector_type(4))) float f32x4;

// Shapes fixed: B=2, S=2048, D=1024, H=16, hd=64, F=2048.
// BOTH batches processed concurrently where scratch allows.
// 8 slots of 4MB (M2 = 2M bf16 elems): r0..r3 (ws), P0a/P0b (=pb0),
// P1a/P1b (=pb1). Slot lifetimes audited per dispatch (see r9 header).
// r11: attn reverted to the proven QBLK=64 kernel (r10's QBLK=128 halved
// the grid to 2 blocks/CU and lost the TLP that hides its latency chain);
// r10's prep2+W3T merge kept.

__device__ inline float toF(float x) { return x; }
__device__ inline float toF(bf16 x) { return __bfloat162float(x); }

__device__ __forceinline__ void unpack8(uint4 u, float* f) {
    f[0] = __uint_as_float(u.x << 16); f[1] = __uint_as_float(u.x & 0xffff0000u);
    f[2] = __uint_as_float(u.y << 16); f[3] = __uint_as_float(u.y & 0xffff0000u);
    f[4] = __uint_as_float(u.z << 16); f[5] = __uint_as_float(u.z & 0xffff0000u);
    f[6] = __uint_as_float(u.w << 16); f[7] = __uint_as_float(u.w & 0xffff0000u);
}

__device__ __forceinline__ uint4 packbf8(const float* f) {
    union { unsigned short u[8]; uint4 v; } r;
#pragma unroll
    for (int i = 0; i < 8; i++) {
        bf16 b = __float2bfloat16(f[i]);
        r.u[i] = *(unsigned short*)&b;
    }
    return r.v;
}

__device__ __forceinline__ unsigned pack2(float lo, float hi) {
    bf16 a = __float2bfloat16(lo), b = __float2bfloat16(hi);
    return ((unsigned)*(unsigned short*)&b << 16) | (unsigned)*(unsigned short*)&a;
}

__device__ __forceinline__ void gl_lds16(const void* g, void* l) {
    __builtin_amdgcn_global_load_lds(
        (__attribute__((address_space(1))) void*)g,
        (__attribute__((address_space(3))) void*)l, 16, 0, 0);
}

// ---------------------------------------------------------------------------
// LN body: one block per row, D=1024, 256 threads.
// ---------------------------------------------------------------------------
template <typename Tx>
__device__ __forceinline__ void ln_body(
    const Tx* __restrict__ x, const float* __restrict__ g,
    const float* __restrict__ b, bf16* __restrict__ out, int row,
    float* s1, float* s2)
{
    const int D = 1024;
    int tid = threadIdx.x;
    const Tx* xr = x + (size_t)row * D;

    float vals[4];
    float sum = 0.f, sumsq = 0.f;
#pragma unroll
    for (int i = 0; i < 4; i++) {
        float v = toF(xr[tid + i * 256]);
        vals[i] = v; sum += v; sumsq += v * v;
    }
#pragma unroll
    for (int off = 32; off > 0; off >>= 1) {
        sum += __shfl_xor(sum, off);
        sumsq += __shfl_xor(sumsq, off);
    }
    int wave = tid >> 6, lane = tid & 63;
    if (lane == 0) { s1[wave] = sum; s2[wave] = sumsq; }
    __syncthreads();
    sum = s1[0] + s1[1] + s1[2] + s1[3];
    sumsq = s2[0] + s2[1] + s2[2] + s2[3];

    float mu = sum * (1.f / D);
    float var = sumsq * (1.f / D) - mu * mu;
    float rstd = rsqrtf(var + 1e-5f);

    bf16* orow = out + (size_t)row * D;
#pragma unroll
    for (int i = 0; i < 4; i++) {
        int c = tid + i * 256;
        orow[c] = __float2bfloat16((vals[i] - mu) * rstd * g[c] + b[c]);
    }
}

// ---------------------------------------------------------------------------
// prep1F: blocks [0,4096): LN1 rows, both batches (b = bx>>11)
//         blocks [4096,7168): WqT/WkT/WvT transpose (48 z-slices)
// ---------------------------------------------------------------------------
__global__ __launch_bounds__(256) void prep1_kernel(
    const float* __restrict__ x, const float* __restrict__ g,
    const float* __restrict__ b, bf16* __restrict__ h0, bf16* __restrict__ h1,
    const float* __restrict__ Wq, const float* __restrict__ Wk,
    const float* __restrict__ Wv, bf16* __restrict__ wt)
{
    __shared__ float t[32][33];
    __shared__ float s1[4], s2[4];
    int bx = blockIdx.x;
    if (bx < 4096) {
        int bb = bx >> 11, row = bx & 2047;
        ln_body<float>(x + ((size_t)bb << 21), g, b, bb ? h1 : h0, row, s1, s2);
        return;
    }
    int zz = bx - 4096;
    int z = zz >> 6, rem = zz & 63;
    int yy = rem >> 1, xx = rem & 1;
    const float* s = (z < 16) ? Wq : (z < 32) ? Wk : Wv;
    const float* ip = s + (size_t)(z & 15) * 65536;
    bf16* op = wt + ((size_t)z << 16);
    int c0 = xx * 32, r0 = yy * 32;
    int tx = threadIdx.x & 31, ty = threadIdx.x >> 5;
#pragma unroll
    for (int i = 0; i < 4; i++)
        t[ty + 8 * i][tx] = ip[(size_t)(r0 + ty + 8 * i) * 64 + c0 + tx];
    __syncthreads();
#pragma unroll
    for (int i = 0; i < 4; i++)
        op[(size_t)(c0 + ty + 8 * i) * 1024 + r0 + tx] = __float2bfloat16(t[tx][ty + 8 * i]);
}

// ---------------------------------------------------------------------------
// prep2: blocks [0,2048): LN2 row (bf16 x2 -> bf16 h2)
//        blocks [2048,6144): W1T/W2T transpose ([1024][2048] -> [2048][1024])
//        blocks [6144,8192): W3T transpose (only in batch-0's 8192 grid)
// ---------------------------------------------------------------------------
__global__ __launch_bounds__(256) void prep2_kernel(
    const bf16* __restrict__ x2, const float* __restrict__ g,
    const float* __restrict__ b, bf16* __restrict__ h2,
    const float* __restrict__ W1, const float* __restrict__ W2,
    bf16* __restrict__ wt, const float* __restrict__ W3,
    bf16* __restrict__ w3t)
{
    __shared__ float t[32][33];
    __shared__ float s1[4], s2[4];
    int bx = blockIdx.x;
    if (bx < 2048) {
        ln_body<bf16>(x2, g, b, h2, bx, s1, s2);
        return;
    }
    int tx = threadIdx.x & 31, ty = threadIdx.x >> 5;
    int zz = bx - 2048;
    if (zz < 4096) {
        int xx = zz & 63, yy = (zz >> 6) & 31, z = zz >> 11;
        const float* ip = z ? W2 : W1;
        bf16* op = wt + ((size_t)z << 21);
        int c0 = xx * 32, r0 = yy * 32;
#pragma unroll
        for (int i = 0; i < 4; i++)
            t[ty + 8 * i][tx] = ip[(size_t)(r0 + ty + 8 * i) * 2048 + c0 + tx];
        __syncthreads();
#pragma unroll
        for (int i = 0; i < 4; i++)
            op[(size_t)(c0 + ty + 8 * i) * 1024 + r0 + tx] = __float2bfloat16(t[tx][ty + 8 * i]);
        return;
    }
    // W3T: [2048][1024] fp32 -> [1024][2048] bf16
    int idx = zz - 4096;
    int xx = idx & 31, yy = idx >> 5;
    int c0 = xx * 32, r0 = yy * 32;
#pragma unroll
    for (int i = 0; i < 4; i++)
        t[ty + 8 * i][tx] = W3[(size_t)(r0 + ty + 8 * i) * 1024 + c0 + tx];
    __syncthreads();
#pragma unroll
    for (int i = 0; i < 4; i++)
        w3t[(size_t)(c0 + ty + 8 * i) * 2048 + r0 + tx] = __float2bfloat16(t[tx][ty + 8 * i]);
}

// ---------------------------------------------------------------------------
// Generic transpose+convert (W3 for batch 1): fp32 [R][C] -> bf16 [C][R].
// ---------------------------------------------------------------------------
__global__ __launch_bounds__(256) void tconv_kernel(
    const float* __restrict__ in, bf16* __restrict__ out, int R, int C)
{
    __shared__ float t[32][33];
    int c0 = blockIdx.x * 32, r0 = blockIdx.y * 32;
    int tx = threadIdx.x & 31, ty = threadIdx.x >> 5;
#pragma unroll
    for (int i = 0; i < 4; i++)
        t[ty + 8 * i][tx] = in[(size_t)(r0 + ty + 8 * i) * C + c0 + tx];
    __syncthreads();
#pragma unroll
    for (int i = 0; i < 4; i++)
        out[(size_t)(c0 + ty + 8 * i) * R + r0 + tx] = __float2bfloat16(t[tx][ty + 8 * i]);
}

// Wo transpose: 16 64-col slices of [1024][1024] -> [64][1024] each.
__global__ __launch_bounds__(256) void tconv_wo_kernel(
    const float* __restrict__ Wo, bf16* __restrict__ out)
{
    __shared__ float t[32][33];
    int z = blockIdx.z;
    const float* ip = Wo + (size_t)z * 64;
    bf16* op = out + ((size_t)z << 16);
    int c0 = blockIdx.x * 32, r0 = blockIdx.y * 32;
    int tx = threadIdx.x & 31, ty = threadIdx.x >> 5;
#pragma unroll
    for (int i = 0; i < 4; i++)
        t[ty + 8 * i][tx] = ip[(size_t)(r0 + ty + 8 * i) * 1024 + c0 + tx];
    __syncthreads();
#pragma unroll
    for (int i = 0; i < 4; i++)
        op[(size_t)(c0 + ty + 8 * i) * 1024 + r0 + tx] = __float2bfloat16(t[tx][ty + 8 * i]);
}

// ---------------------------------------------------------------------------
// MFMA GEMM: C[M,N] = A[M,K](bf16) @ B (BT[N,K] bf16), fp32 accum.
// 64x64 tile, BK=64 double-buffer, 4 waves (2x2), wave tile 32x32.
// Source-pre-swizzled LDS (conflict-free ds_read_b128), setprio around MFMA.
//
// MODE 1 (QKF): z=0..3: bit1=batch (A=A / resv; C=Cv / p6), bit0=q/k
//         (BT0 + bit0*1M; C + bit0*2M). Scatter [H][S][64] + RoPE always.
// MODE 6 (V^T): C written directly as vt[h][d][s] (packed uint2).
// MODE 2 (F):  z=batch: A=A/p5, res=resv fp32 +z*2M, C=Cv/p6; C bf16=acc+res.
// MODE 4: C f32 = acc + resBf16
// MODE 5: fused SwiGLU dual-B (B1=BT0, B2=resv); C bf16 = silu(u)*g. 48KB LDS.
// ---------------------------------------------------------------------------
template <int MODE>
__global__ __launch_bounds__(256) void mfma_gemm(
    const bf16* __restrict__ A, const bf16* __restrict__ BT0,
    void* __restrict__ Cv, const void* __restrict__ resv,
    const void* __restrict__ p5, void* __restrict__ p6,
    int M, int N, int K)
{
    constexpr int NB = (MODE == 5) ? 3 : 2;            // matrices per buffer
    __shared__ bf16 smem[2][NB][64 * 64];              // 32KB / 48KB
    int tid = threadIdx.x, lane = tid & 63, w = tid >> 6;
    int wm = w >> 1, wn = w & 1;
    int m0 = blockIdx.y * 64, n0 = blockIdx.x * 64;

    const bf16* Ap = A;
    const bf16* BT = BT0;
    bf16* Cq = nullptr;
    const float* resF = (const float*)resv;
    void* Cdst = Cv;
    if (MODE == 1) {
        int z = blockIdx.z;
        if (z >> 1) Ap = (const bf16*)resv;            // h1
        BT = BT0 + ((size_t)(z & 1) << 20);
        Cq = (bf16*)((z >> 1) ? p6 : Cv) + ((size_t)(z & 1) << 21);
    }
    if (MODE == 6) Cq = (bf16*)Cv;
    if (MODE == 2) {
        int z = blockIdx.z;
        if (z) { Ap = (const bf16*)p5; Cdst = p6; }
        resF = (const float*)resv + ((size_t)z << 21);
    }

    int lrow = lane >> 3;                  // 0..7
    int lcb  = (lane & 7) ^ lrow;          // pre-swizzled 16B col-block
    const bf16* Ag  = Ap + (size_t)(m0 + w * 8 + lrow) * K + lcb * 8;
    const bf16* Bg0 = BT + (size_t)(n0 + w * 8 + lrow) * K + lcb * 8;
    const bf16* B2g = (MODE == 5)
        ? (const bf16*)resv + (size_t)(n0 + w * 8 + lrow) * K + lcb * 8
        : nullptr;
    unsigned sbase = (unsigned)__builtin_amdgcn_readfirstlane(w * 8 * 128);
    char* smc = (char*)smem;

    f32x4 acc[2][2], acc2[2][2];
#pragma unroll
    for (int i = 0; i < 2; i++)
#pragma unroll
        for (int j = 0; j < 2; j++) {
            acc[i][j] = (f32x4){0.f, 0.f, 0.f, 0.f};
            if (MODE == 5) acc2[i][j] = (f32x4){0.f, 0.f, 0.f, 0.f};
        }

    int cidx = lane & 15, quad = lane >> 4;

    auto STAGE = [&](int buf, int k0) {
        char* p = smc + (size_t)buf * (NB * 8192) + sbase;
        gl_lds16(Ag + k0,                   p);
        gl_lds16(Ag + (size_t)32 * K + k0,  p + 4096);
        gl_lds16(Bg0 + k0,                  p + 8192);
        gl_lds16(Bg0 + (size_t)32 * K + k0, p + 12288);
        if (MODE == 5) {
            gl_lds16(B2g + k0,                  p + 16384);
            gl_lds16(B2g + (size_t)32 * K + k0, p + 20480);
        }
    };

    STAGE(0, 0);
    __syncthreads();                 // drains vmcnt, publishes buf0
    int cur = 0;
    for (int k0 = 0; k0 < K; k0 += 64) {
        if (k0 + 64 < K) STAGE(cur ^ 1, k0 + 64);   // prefetch next
        const bf16* Ab = (const bf16*)(smc + (size_t)cur * (NB * 8192));
        const bf16* Bb = Ab + 4096;
        const bf16* B2b = Ab + 8192;
#pragma unroll
        for (int kk = 0; kk < 2; kk++) {
            int pb = (kk * 4 + quad) ^ (cidx & 7);  // swizzled slot
            bf16x8 af[2], bfr[2], b2f[2];
#pragma unroll
            for (int i = 0; i < 2; i++)
                af[i] = *(const bf16x8*)&Ab[(wm * 32 + i * 16 + cidx) * 64 + pb * 8];
#pragma unroll
            for (int j = 0; j < 2; j++)
                bfr[j] = *(const bf16x8*)&Bb[(wn * 32 + j * 16 + cidx) * 64 + pb * 8];
            if (MODE == 5) {
#pragma unroll
                for (int j = 0; j < 2; j++)
                    b2f[j] = *(const bf16x8*)&B2b[(wn * 32 + j * 16 + cidx) * 64 + pb * 8];
            }
            __builtin_amdgcn_s_setprio(1);
#pragma unroll
            for (int i = 0; i < 2; i++)
#pragma unroll
                for (int j = 0; j < 2; j++) {
                    acc[i][j] = __builtin_amdgcn_mfma_f32_16x16x32_bf16(af[i], bfr[j], acc[i][j], 0, 0, 0);
                    if (MODE == 5)
                        acc2[i][j] = __builtin_amdgcn_mfma_f32_16x16x32_bf16(af[i], b2f[j], acc2[i][j], 0, 0, 0);
                }
            __builtin_amdgcn_s_setprio(0);
        }
        __syncthreads();             // reads of cur done + prefetch landed
        cur ^= 1;
    }

    int rbase = quad * 4;
#pragma unroll
    for (int i = 0; i < 2; i++) {
#pragma unroll
        for (int j = 0; j < 2; j++) {
            int row0 = m0 + wm * 32 + i * 16 + rbase;
            int col = n0 + wn * 32 + j * 16 + cidx;
            if (MODE == 6) {
                // direct V^T write vt[h][d][s], 4 consecutive s packed
                int h_ = col >> 6, d = col & 63;
                uint2 t;
                t.x = pack2(acc[i][j][0], acc[i][j][1]);
                t.y = pack2(acc[i][j][2], acc[i][j][3]);
                *(uint2*)&Cq[(size_t)h_ * 131072 + (size_t)d * 2048 + row0] = t;
                continue;
            }
#pragma unroll
            for (int r = 0; r < 4; r++) {
                int row = row0 + r;
                float v = acc[i][j][r];
                size_t idx = (size_t)row * N + col;
                if (MODE == 1) {
                    int h_ = col >> 6, kk = col & 63;
                    float other = __shfl_xor(v, 1);
                    float p = (float)(kk >> 1);
                    float theta = __expf(p * -0.5756462732485114f); // ln(1e4)/16
                    float ang = (float)row * theta;
                    float c, sn; __sincosf(ang, &sn, &c);
                    float outv = (kk & 1) ? (v * c + other * sn) : (v * c - other * sn);
                    Cq[((size_t)h_ * 2048 + row) * 64 + kk] = __float2bfloat16(outv);
                } else if (MODE == 2) {
                    v += resF[idx];
                    ((bf16*)Cdst)[idx] = __float2bfloat16(v);
                } else if (MODE == 5) {
                    float g2 = acc2[i][j][r];
                    float sg = 1.f / (1.f + __expf(-v));
                    ((bf16*)Cv)[idx] = __float2bfloat16(v * sg * g2);
                } else {
                    v += __bfloat162float(((const bf16*)resv)[idx]);
                    ((float*)Cv)[idx] = v;
                }
            }
        }
    }
}

// ---------------------------------------------------------------------------
// MFMA causal flash attention, BOTH batches (z = batch). hd=64. QBLK=64,
// KVBLK=64 (r9-proven operating point: grid 1024 = 4 blocks/CU).
// Reg-prefetch + 2 barriers, XOR-swizzled [64][64] K/V LDS, deferred-l +
// defer-max log2 softmax, P^T wave-private strip.
// ---------------------------------------------------------------------------
__global__ __launch_bounds__(256) void attn_kernel(
    const bf16* __restrict__ q0, const bf16* __restrict__ k0,
    const bf16* __restrict__ vt0, bf16* __restrict__ o0,
    const bf16* __restrict__ q1, const bf16* __restrict__ k1,
    const bf16* __restrict__ vt1, bf16* __restrict__ o1)
{
    const int S = 2048;
    __shared__ bf16 Ks[64 * 64];
    __shared__ bf16 Vs[64 * 64];
    __shared__ __align__(16) char QPbuf[64 * 72 * 2];

    int zb = blockIdx.z;
    const bf16* q = zb ? q1 : q0;
    const bf16* k = zb ? k1 : k0;
    const bf16* vt = zb ? vt1 : vt0;
    bf16* o = zb ? o1 : o0;

    int h = blockIdx.y;
    int qt = (h & 8) ? (int)blockIdx.x : 31 - (int)blockIdx.x;
    int tid = threadIdx.x, lane = tid & 63, w = tid >> 6;
    int quad = lane >> 4, cidx = lane & 15;
    int m0 = qt * 64;

    const bf16* qb = q + ((size_t)h * S + m0) * 64;
    const bf16* kb = k + (size_t)h * S * 64;
    const bf16* vtb = vt + (size_t)h * 64 * S;

    int srow = tid >> 2;
    int sg = (tid & 3) * 16;

    bf16 (*Qs)[72] = (bf16 (*)[72])QPbuf;
    {
        const uint4* src = (const uint4*)(qb + (size_t)srow * 64 + sg);
        uint4 u0 = src[0], u1 = src[1];
        float f[16]; unpack8(u0, f); unpack8(u1, f + 8);
#pragma unroll
        for (int i = 0; i < 16; i++) f[i] *= 0.125f * 1.44269504f;
        *(uint4*)&Qs[srow][sg] = packbf8(f);
        *(uint4*)&Qs[srow][sg + 8] = packbf8(f + 8);
    }
    bf16x8 bQ0 = *(const bf16x8*)&Qs[w * 16 + cidx][quad * 8];
    bf16x8 bQ1 = *(const bf16x8*)&Qs[w * 16 + cidx][32 + quad * 8];

    unsigned* Pst = (unsigned*)QPbuf + w * 576;

    int cb0 = (tid & 3) * 2;
    int sw0 = ((cb0)     ^ (srow & 7)) * 8;
    int sw1 = ((cb0 + 1) ^ (srow & 7)) * 8;
    int pb0 = ((quad)     ^ (cidx & 7)) * 8;
    int pb1 = ((4 + quad) ^ (cidx & 7)) * 8;

    float m_i = -INFINITY, l_i = 0.f;
    f32x4 Oc[4];
#pragma unroll
    for (int i = 0; i < 4; i++) Oc[i] = (f32x4){0.f, 0.f, 0.f, 0.f};

    uint4 ka0, ka1, va0, va1;
    {
        const uint4* ksrc = (const uint4*)(kb + (size_t)srow * 64 + sg);
        ka0 = ksrc[0]; ka1 = ksrc[1];
        const uint4* vsrc = (const uint4*)(vtb + (size_t)srow * S + sg);
        va0 = vsrc[0]; va1 = vsrc[1];
    }

    for (int kt = 0; kt <= qt; kt++) {
        __syncthreads();
        *(uint4*)&Ks[srow * 64 + sw0] = ka0;
        *(uint4*)&Ks[srow * 64 + sw1] = ka1;
        *(uint4*)&Vs[srow * 64 + sw0] = va0;
        *(uint4*)&Vs[srow * 64 + sw1] = va1;
        __syncthreads();
        if (kt < qt) {
            const uint4* kn = (const uint4*)(kb + (size_t)((kt + 1) * 64 + srow) * 64 + sg);
            ka0 = kn[0]; ka1 = kn[1];
            const uint4* vn = (const uint4*)(vtb + (size_t)srow * S + (kt + 1) * 64 + sg);
            va0 = vn[0]; va1 = vn[1];
        }

        f32x4 sc[4];
#pragma unroll
        for (int i = 0; i < 4; i++) {
            bf16x8 aK0 = *(const bf16x8*)&Ks[(i * 16 + cidx) * 64 + pb0];
            bf16x8 aK1 = *(const bf16x8*)&Ks[(i * 16 + cidx) * 64 + pb1];
            f32x4 z = (f32x4){0.f, 0.f, 0.f, 0.f};
            __builtin_amdgcn_s_setprio(1);
            z = __builtin_amdgcn_mfma_f32_16x16x32_bf16(aK0, bQ0, z, 0, 0, 0);
            z = __builtin_amdgcn_mfma_f32_16x16x32_bf16(aK1, bQ1, z, 0, 0, 0);
            __builtin_amdgcn_s_setprio(0);
            sc[i] = z;
        }

        if (kt == qt) {
#pragma unroll
            for (int i = 0; i < 4; i++)
#pragma unroll
                for (int r = 0; r < 4; r++)
                    if (i * 16 + quad * 4 + r > w * 16 + cidx) sc[i][r] = -INFINITY;
        }

        float l0 = fmaxf(fmaxf(sc[0][0], sc[0][1]), fmaxf(sc[0][2], sc[0][3]));
        float l1 = fmaxf(fmaxf(sc[1][0], sc[1][1]), fmaxf(sc[1][2], sc[1][3]));
        float l2 = fmaxf(fmaxf(sc[2][0], sc[2][1]), fmaxf(sc[2][2], sc[2][3]));
        float l3 = fmaxf(fmaxf(sc[3][0], sc[3][1]), fmaxf(sc[3][2], sc[3][3]));
        float lmax = fmaxf(fmaxf(l0, l1), fmaxf(l2, l3));

        if (!__all(lmax <= m_i + 8.f)) {
            float pmax = fmaxf(lmax, __shfl_xor(lmax, 16));
            pmax = fmaxf(pmax, __shfl_xor(pmax, 32));
            float mnew = fmaxf(m_i, pmax);
            float alpha = __builtin_amdgcn_exp2f(m_i - mnew);
            l_i *= alpha;
#pragma unroll
            for (int i = 0; i < 4; i++) {
                Oc[i][0] *= alpha; Oc[i][1] *= alpha;
                Oc[i][2] *= alpha; Oc[i][3] *= alpha;
            }
            m_i = mnew;
        }

        float rs = 0.f;
#pragma unroll
        for (int i = 0; i < 4; i++)
#pragma unroll
            for (int r = 0; r < 4; r++) {
                sc[i][r] = __builtin_amdgcn_exp2f(sc[i][r] - m_i);
                rs += sc[i][r];
            }
        l_i += rs;

#pragma unroll
        for (int i = 0; i < 4; i++) {
            uint2 t;
            t.x = pack2(sc[i][0], sc[i][1]);
            t.y = pack2(sc[i][2], sc[i][3]);
            *(uint2*)&Pst[cidx * 36 + 8 * i + 2 * quad] = t;
        }
        bf16x8 bP0 = *(const bf16x8*)&Pst[cidx * 36 + 4 * quad];
        bf16x8 bP1 = *(const bf16x8*)&Pst[cidx * 36 + 16 + 4 * quad];

#pragma unroll
        for (int i = 0; i < 4; i++) {
            bf16x8 aV0 = *(const bf16x8*)&Vs[(i * 16 + cidx) * 64 + pb0];
            bf16x8 aV1 = *(const bf16x8*)&Vs[(i * 16 + cidx) * 64 + pb1];
            __builtin_amdgcn_s_setprio(1);
            Oc[i] = __builtin_amdgcn_mfma_f32_16x16x32_bf16(aV0, bP0, Oc[i], 0, 0, 0);
            Oc[i] = __builtin_amdgcn_mfma_f32_16x16x32_bf16(aV1, bP1, Oc[i], 0, 0, 0);
            __builtin_amdgcn_s_setprio(0);
        }
    }

    float lr = l_i;
    lr += __shfl_xor(lr, 16);
    lr += __shfl_xor(lr, 32);
    float inv = 1.f / lr;
#pragma unroll
    for (int i = 0; i < 4; i++) {
        uint2 t;
        t.x = pack2(Oc[i][0] * inv, Oc[i][1] * inv);
        t.y = pack2(Oc[i][2] * inv, Oc[i][3] * inv);
        *(uint2*)&Pst[cidx * 36 + 8 * i + 2 * quad] = t;
    }
    int r2 = lane >> 2, g2 = (lane & 3) * 8;
    uint4 o0v = *(const uint4*)&Pst[r2 * 36 + g2];
    uint4 o1v = *(const uint4*)&Pst[r2 * 36 + g2 + 4];
    bf16* orow = o + (size_t)(m0 + w * 16 + r2) * 1024 + h * 64;
    *(uint4*)(orow + g2 * 2) = o0v;
    *(uint4*)(orow + g2 * 2 + 8) = o1v;
}

// ---------------------------------------------------------------------------
extern "C" void kernel_launch(void* const* d_in, const int* in_sizes, int n_in,
                              void* d_out, int out_size, void* d_ws, size_t ws_size,
                              hipStream_t stream)
{
    const int S = 2048;

    const float* x    = (const float*)d_in[0];
    const float* ln1g = (const float*)d_in[1];
    const float* ln1b = (const float*)d_in[2];
    const float* Wq   = (const float*)d_in[3];
    const float* Wk   = (const float*)d_in[4];
    const float* Wv   = (const float*)d_in[5];
    const float* Wo   = (const float*)d_in[6];
    const float* ln2g = (const float*)d_in[7];
    const float* ln2b = (const float*)d_in[8];
    const float* W1   = (const float*)d_in[9];
    const float* W2   = (const float*)d_in[10];
    const float* W3   = (const float*)d_in[11];
    float* out = (float*)d_out;

    const size_t M2 = 1u << 21;        // 2M bf16 elems (one 4MB slot)
    bf16* r0 = (bf16*)d_ws;
    bf16* r1 = r0 + M2;
    bf16* r2 = r1 + M2;
    bf16* r3 = r2 + M2;
    bf16* pb0 = (bf16*)out;            // P0a = pb0, P0b = pb0+M2
    bf16* pb1 = pb0 + 2 * M2;          // P1a = pb1, P1b = pb1+M2
    float* out0 = out;
    float* out1 = out + (1u << 21);    // batch-1 output (2M floats offset)

    // 1. LN1 both -> r0,r1; WqT/WkT/WvT -> pb0[0:3M elems)
    prep1_kernel<<<7168, 256, 0, stream>>>(x, ln1g, ln1b, r0, r1,
                                           Wq, Wk, Wv, pb0);

    // 2. QKF: q0->r2, k0->r3, q1->P1a, k1->P1b (RoPE all)
    mfma_gemm<1><<<dim3(16, 32, 4), 256, 0, stream>>>(
        r0, pb0, r2, r1, nullptr, pb1, S, 1024, 1024);

    // 3. vt0 = (h0 @ Wv)^T -> pb0[0:M2)  (WvT at pb0+M2; WqT/WkT dead)
    mfma_gemm<6><<<dim3(16, 32, 1), 256, 0, stream>>>(
        r0, pb0 + M2, pb0, nullptr, nullptr, nullptr, S, 1024, 1024);

    // 4. vt1 -> r0 (h0 dead)
    mfma_gemm<6><<<dim3(16, 32, 1), 256, 0, stream>>>(
        r1, pb0 + M2, r0, nullptr, nullptr, nullptr, S, 1024, 1024);

    // 5. attnF: ao0 -> r1 (h1 dead), ao1 -> pb0+M2 (WvT dead)
    attn_kernel<<<dim3(32, 16, 2), 256, 0, stream>>>(
        r2, r3, pb0, r1, pb1, pb1 + M2, r0, pb0 + M2);

    // 6a. WoT -> r2 (q0 dead)
    tconv_wo_kernel<<<dim3(2, 32, 16), 256, 0, stream>>>(Wo, r2);

    // 6b. mode2F: x2_0 = x0 + ao0@Wo -> r3 (k0 dead); x2_1 -> r0 (vt1 dead)
    mfma_gemm<2><<<dim3(16, 32, 2), 256, 0, stream>>>(
        r1, r2, r3, x, pb0 + M2, r0, S, 1024, 1024);

    // 7a. prep2(b0)+W3T: h2_0 -> P1a (q1 dead); W1T->pb0, W2T->pb0+M2;
    //     W3T -> P1b (k1 dead)
    prep2_kernel<<<8192, 256, 0, stream>>>(r3, ln2g, ln2b, pb1, W1, W2, pb0,
                                           W3, pb1 + M2);

    // 7b. mode5(b0): sb0 = silu(h2_0@W1)*(h2_0@W2) -> r1..r2
    mfma_gemm<5><<<dim3(32, 32, 1), 256, 0, stream>>>(
        pb1, pb0, r1, pb0 + M2, nullptr, nullptr, S, 2048, 1024);

    // 7d. out0 = x2_0 + sb0@W3 -> pb0 fp32 (W12T dead)
    mfma_gemm<4><<<dim3(16, 32, 1), 256, 0, stream>>>(
        r1, pb1 + M2, out0, r3, nullptr, nullptr, S, 1024, 2048);

    // 8a. prep2(b1): x2_1=r0 -> h2_1 -> r3 (x2_0 dead); W12T -> pb1
    prep2_kernel<<<6144, 256, 0, stream>>>(r0, ln2g, ln2b, r3, W1, W2, pb1,
                                           nullptr, nullptr);

    // 8b. mode5(b1): sb1 -> r1..r2 (sb0 dead)
    mfma_gemm<5><<<dim3(32, 32, 1), 256, 0, stream>>>(
        r3, pb1, r1, pb1 + M2, nullptr, nullptr, S, 2048, 1024);

    // 8c. W3T -> r3 (h2_1 dead)
    tconv_kernel<<<dim3(32, 64), 256, 0, stream>>>(W3, r3, 2048, 1024);

    // 8d. out1 = x2_1 + sb1@W3 -> pb1 fp32 (W12T dead)
    mfma_gemm<4><<<dim3(16, 32, 1), 256, 0, stream>>>(
        r1, r3, out1, r0, nullptr, nullptr, S, 1024, 2048);
}

// Round 12
// 312.244 us; speedup vs baseline: 1.0758x; 1.0663x over previous
//
#include <hip/hip_runtime.h>
#include <hip/hip_bf16.h>

using bf16 = __hip_bfloat16;
typedef __attribute__((ext_vector_type(8))) short bf16x8;
typedef __attribute__((ext_vector_type(4))) float f32x4;

// Shapes fixed: B=2, S=2048, D=1024, H=16, hd=64, F=2048.
// 8 slots of 4MB (M2 = 2M bf16 elems): r0..r3 (ws), pb0 a/b, pb1 a/b (out).
// r12 front-end (audited): 
//  1 prep1F: h0->r0, h1->r1; WqT->pb0[0:1M), WkT->[1M:2M), WvT->[2M:3M)
//  2 mode6F z=2: vt0->P1a(pb1), vt1->P1b (inputs r0,r1,WvT)
//  3 QK(b0) z=2: q0->r2, k0->r3 (A=r0; WqT/WkT)
//  4 QK(b1) z=2: q1->r0 (h0 dead), k1->pb0+M2 (WvT dead)
//  5 attnF: ao0->r1 (h1 dead), ao1->pb0 (WqT/WkT dead)
//  6a WoT->r2 (q0 dead); 6b mode2F: x2_0->r3 (k0 dead), x2_1->r0 (q1 dead)
// back-end (identical to r11):
//  7a prep2(b0): h2_0->P1a (vt0 dead); W12T->pb0 (ao1/k1 dead); W3T->P1b
//  7b swiglu(b0): sb0 -> r1..r2 (ao0, WoT dead)   [retiled 128x64]
//  7d mode4(b0): out0 -> pb0 fp32 (W12T dead)
//  8a prep2(b1): h2_1->r3 (x2_0 dead); W12T->pb1 (h2_0, W3T dead)
//  8b swiglu(b1): sb1 -> r1..r2   8c W3T->r3   8d out1->pb1 (res=r0)

__device__ inline float toF(float x) { return x; }
__device__ inline float toF(bf16 x) { return __bfloat162float(x); }

__device__ __forceinline__ void unpack8(uint4 u, float* f) {
    f[0] = __uint_as_float(u.x << 16); f[1] = __uint_as_float(u.x & 0xffff0000u);
    f[2] = __uint_as_float(u.y << 16); f[3] = __uint_as_float(u.y & 0xffff0000u);
    f[4] = __uint_as_float(u.z << 16); f[5] = __uint_as_float(u.z & 0xffff0000u);
    f[6] = __uint_as_float(u.w << 16); f[7] = __uint_as_float(u.w & 0xffff0000u);
}

__device__ __forceinline__ uint4 packbf8(const float* f) {
    union { unsigned short u[8]; uint4 v; } r;
#pragma unroll
    for (int i = 0; i < 8; i++) {
        bf16 b = __float2bfloat16(f[i]);
        r.u[i] = *(unsigned short*)&b;
    }
    return r.v;
}

__device__ __forceinline__ unsigned pack2(float lo, float hi) {
    bf16 a = __float2bfloat16(lo), b = __float2bfloat16(hi);
    return ((unsigned)*(unsigned short*)&b << 16) | (unsigned)*(unsigned short*)&a;
}

__device__ __forceinline__ void gl_lds16(const void* g, void* l) {
    __builtin_amdgcn_global_load_lds(
        (__attribute__((address_space(1))) void*)g,
        (__attribute__((address_space(3))) void*)l, 16, 0, 0);
}

// ---------------------------------------------------------------------------
// LN body: one block per row, D=1024, 256 threads.
// ---------------------------------------------------------------------------
template <typename Tx>
__device__ __forceinline__ void ln_body(
    const Tx* __restrict__ x, const float* __restrict__ g,
    const float* __restrict__ b, bf16* __restrict__ out, int row,
    float* s1, float* s2)
{
    const int D = 1024;
    int tid = threadIdx.x;
    const Tx* xr = x + (size_t)row * D;

    float vals[4];
    float sum = 0.f, sumsq = 0.f;
#pragma unroll
    for (int i = 0; i < 4; i++) {
        float v = toF(xr[tid + i * 256]);
        vals[i] = v; sum += v; sumsq += v * v;
    }
#pragma unroll
    for (int off = 32; off > 0; off >>= 1) {
        sum += __shfl_xor(sum, off);
        sumsq += __shfl_xor(sumsq, off);
    }
    int wave = tid >> 6, lane = tid & 63;
    if (lane == 0) { s1[wave] = sum; s2[wave] = sumsq; }
    __syncthreads();
    sum = s1[0] + s1[1] + s1[2] + s1[3];
    sumsq = s2[0] + s2[1] + s2[2] + s2[3];

    float mu = sum * (1.f / D);
    float var = sumsq * (1.f / D) - mu * mu;
    float rstd = rsqrtf(var + 1e-5f);

    bf16* orow = out + (size_t)row * D;
#pragma unroll
    for (int i = 0; i < 4; i++) {
        int c = tid + i * 256;
        orow[c] = __float2bfloat16((vals[i] - mu) * rstd * g[c] + b[c]);
    }
}

// ---------------------------------------------------------------------------
// prep1F: blocks [0,4096): LN1 rows, both batches (b = bx>>11)
//         blocks [4096,7168): WqT/WkT/WvT transpose (48 z-slices)
// ---------------------------------------------------------------------------
__global__ __launch_bounds__(256) void prep1_kernel(
    const float* __restrict__ x, const float* __restrict__ g,
    const float* __restrict__ b, bf16* __restrict__ h0, bf16* __restrict__ h1,
    const float* __restrict__ Wq, const float* __restrict__ Wk,
    const float* __restrict__ Wv, bf16* __restrict__ wt)
{
    __shared__ float t[32][33];
    __shared__ float s1[4], s2[4];
    int bx = blockIdx.x;
    if (bx < 4096) {
        int bb = bx >> 11, row = bx & 2047;
        ln_body<float>(x + ((size_t)bb << 21), g, b, bb ? h1 : h0, row, s1, s2);
        return;
    }
    int zz = bx - 4096;
    int z = zz >> 6, rem = zz & 63;
    int yy = rem >> 1, xx = rem & 1;
    const float* s = (z < 16) ? Wq : (z < 32) ? Wk : Wv;
    const float* ip = s + (size_t)(z & 15) * 65536;
    bf16* op = wt + ((size_t)z << 16);
    int c0 = xx * 32, r0 = yy * 32;
    int tx = threadIdx.x & 31, ty = threadIdx.x >> 5;
#pragma unroll
    for (int i = 0; i < 4; i++)
        t[ty + 8 * i][tx] = ip[(size_t)(r0 + ty + 8 * i) * 64 + c0 + tx];
    __syncthreads();
#pragma unroll
    for (int i = 0; i < 4; i++)
        op[(size_t)(c0 + ty + 8 * i) * 1024 + r0 + tx] = __float2bfloat16(t[tx][ty + 8 * i]);
}

// ---------------------------------------------------------------------------
// prep2: blocks [0,2048): LN2 row (bf16 x2 -> bf16 h2)
//        blocks [2048,6144): W1T/W2T transpose
//        blocks [6144,8192): W3T transpose (batch-0 grid only)
// ---------------------------------------------------------------------------
__global__ __launch_bounds__(256) void prep2_kernel(
    const bf16* __restrict__ x2, const float* __restrict__ g,
    const float* __restrict__ b, bf16* __restrict__ h2,
    const float* __restrict__ W1, const float* __restrict__ W2,
    bf16* __restrict__ wt, const float* __restrict__ W3,
    bf16* __restrict__ w3t)
{
    __shared__ float t[32][33];
    __shared__ float s1[4], s2[4];
    int bx = blockIdx.x;
    if (bx < 2048) {
        ln_body<bf16>(x2, g, b, h2, bx, s1, s2);
        return;
    }
    int tx = threadIdx.x & 31, ty = threadIdx.x >> 5;
    int zz = bx - 2048;
    if (zz < 4096) {
        int xx = zz & 63, yy = (zz >> 6) & 31, z = zz >> 11;
        const float* ip = z ? W2 : W1;
        bf16* op = wt + ((size_t)z << 21);
        int c0 = xx * 32, r0 = yy * 32;
#pragma unroll
        for (int i = 0; i < 4; i++)
            t[ty + 8 * i][tx] = ip[(size_t)(r0 + ty + 8 * i) * 2048 + c0 + tx];
        __syncthreads();
#pragma unroll
        for (int i = 0; i < 4; i++)
            op[(size_t)(c0 + ty + 8 * i) * 1024 + r0 + tx] = __float2bfloat16(t[tx][ty + 8 * i]);
        return;
    }
    int idx = zz - 4096;
    int xx = idx & 31, yy = idx >> 5;
    int c0 = xx * 32, r0 = yy * 32;
#pragma unroll
    for (int i = 0; i < 4; i++)
        t[ty + 8 * i][tx] = W3[(size_t)(r0 + ty + 8 * i) * 1024 + c0 + tx];
    __syncthreads();
#pragma unroll
    for (int i = 0; i < 4; i++)
        w3t[(size_t)(c0 + ty + 8 * i) * 2048 + r0 + tx] = __float2bfloat16(t[tx][ty + 8 * i]);
}

// ---------------------------------------------------------------------------
// Generic transpose+convert (W3 for batch 1): fp32 [R][C] -> bf16 [C][R].
// ---------------------------------------------------------------------------
__global__ __launch_bounds__(256) void tconv_kernel(
    const float* __restrict__ in, bf16* __restrict__ out, int R, int C)
{
    __shared__ float t[32][33];
    int c0 = blockIdx.x * 32, r0 = blockIdx.y * 32;
    int tx = threadIdx.x & 31, ty = threadIdx.x >> 5;
#pragma unroll
    for (int i = 0; i < 4; i++)
        t[ty + 8 * i][tx] = in[(size_t)(r0 + ty + 8 * i) * C + c0 + tx];
    __syncthreads();
#pragma unroll
    for (int i = 0; i < 4; i++)
        out[(size_t)(c0 + ty + 8 * i) * R + r0 + tx] = __float2bfloat16(t[tx][ty + 8 * i]);
}

// Wo transpose: 16 64-col slices of [1024][1024] -> [64][1024] each.
__global__ __launch_bounds__(256) void tconv_wo_kernel(
    const float* __restrict__ Wo, bf16* __restrict__ out)
{
    __shared__ float t[32][33];
    int z = blockIdx.z;
    const float* ip = Wo + (size_t)z * 64;
    bf16* op = out + ((size_t)z << 16);
    int c0 = blockIdx.x * 32, r0 = blockIdx.y * 32;
    int tx = threadIdx.x & 31, ty = threadIdx.x >> 5;
#pragma unroll
    for (int i = 0; i < 4; i++)
        t[ty + 8 * i][tx] = ip[(size_t)(r0 + ty + 8 * i) * 1024 + c0 + tx];
    __syncthreads();
#pragma unroll
    for (int i = 0; i < 4; i++)
        op[(size_t)(c0 + ty + 8 * i) * 1024 + r0 + tx] = __float2bfloat16(t[tx][ty + 8 * i]);
}

// ---------------------------------------------------------------------------
// MFMA GEMM: C[M,N] = A[M,K](bf16) @ B (BT[N,K] bf16), fp32 accum.
// 64x64 tile, BK=64 double-buffer, 4 waves (2x2), wave tile 32x32.
// Source-pre-swizzled LDS, setprio around MFMA.
// MODE 1 (QK, one batch): z=0/1 = q/k: BT=BT0+z*1M; C = z ? p6 : Cv.
//        Scatter [H][S][64] + RoPE always.
// MODE 6 (V^T, both batches): z=0: A,Cv; z=1: p5,p6. vt[h][d][s] direct.
// MODE 2 (F): z=batch: A=A/p5, res=resv fp32 +z*2M, C=Cv/p6; bf16=acc+res.
// MODE 4: C f32 = acc + resBf16
// ---------------------------------------------------------------------------
template <int MODE>
__global__ __launch_bounds__(256) void mfma_gemm(
    const bf16* __restrict__ A, const bf16* __restrict__ BT0,
    void* __restrict__ Cv, const void* __restrict__ resv,
    const void* __restrict__ p5, void* __restrict__ p6,
    int M, int N, int K)
{
    __shared__ bf16 smem[2][2][64 * 64];               // 32KB
    int tid = threadIdx.x, lane = tid & 63, w = tid >> 6;
    int wm = w >> 1, wn = w & 1;
    int m0 = blockIdx.y * 64, n0 = blockIdx.x * 64;

    const bf16* Ap = A;
    const bf16* BT = BT0;
    bf16* Cq = nullptr;
    const float* resF = (const float*)resv;
    void* Cdst = Cv;
    if (MODE == 1) {
        int z = blockIdx.z;
        BT = BT0 + ((size_t)z << 20);
        Cq = (bf16*)(z ? p6 : Cv);
    }
    if (MODE == 6) {
        int z = blockIdx.z;
        if (z) { Ap = (const bf16*)p5; Cq = (bf16*)p6; }
        else Cq = (bf16*)Cv;
    }
    if (MODE == 2) {
        int z = blockIdx.z;
        if (z) { Ap = (const bf16*)p5; Cdst = p6; }
        resF = (const float*)resv + ((size_t)z << 21);
    }

    int lrow = lane >> 3;
    int lcb  = (lane & 7) ^ lrow;
    const bf16* Ag  = Ap + (size_t)(m0 + w * 8 + lrow) * K + lcb * 8;
    const bf16* Bg0 = BT + (size_t)(n0 + w * 8 + lrow) * K + lcb * 8;
    unsigned sbase = (unsigned)__builtin_amdgcn_readfirstlane(w * 8 * 128);
    char* smc = (char*)smem;

    f32x4 acc[2][2];
#pragma unroll
    for (int i = 0; i < 2; i++)
#pragma unroll
        for (int j = 0; j < 2; j++) acc[i][j] = (f32x4){0.f, 0.f, 0.f, 0.f};

    int cidx = lane & 15, quad = lane >> 4;

    auto STAGE = [&](int buf, int k0) {
        char* p = smc + (size_t)buf * 16384 + sbase;
        gl_lds16(Ag + k0,                   p);
        gl_lds16(Ag + (size_t)32 * K + k0,  p + 4096);
        gl_lds16(Bg0 + k0,                  p + 8192);
        gl_lds16(Bg0 + (size_t)32 * K + k0, p + 12288);
    };

    STAGE(0, 0);
    __syncthreads();
    int cur = 0;
    for (int k0 = 0; k0 < K; k0 += 64) {
        if (k0 + 64 < K) STAGE(cur ^ 1, k0 + 64);
        const bf16* Ab = (const bf16*)(smc + (size_t)cur * 16384);
        const bf16* Bb = Ab + 4096;
#pragma unroll
        for (int kk = 0; kk < 2; kk++) {
            int pb = (kk * 4 + quad) ^ (cidx & 7);
            bf16x8 af[2], bfr[2];
#pragma unroll
            for (int i = 0; i < 2; i++)
                af[i] = *(const bf16x8*)&Ab[(wm * 32 + i * 16 + cidx) * 64 + pb * 8];
#pragma unroll
            for (int j = 0; j < 2; j++)
                bfr[j] = *(const bf16x8*)&Bb[(wn * 32 + j * 16 + cidx) * 64 + pb * 8];
            __builtin_amdgcn_s_setprio(1);
#pragma unroll
            for (int i = 0; i < 2; i++)
#pragma unroll
                for (int j = 0; j < 2; j++)
                    acc[i][j] = __builtin_amdgcn_mfma_f32_16x16x32_bf16(af[i], bfr[j], acc[i][j], 0, 0, 0);
            __builtin_amdgcn_s_setprio(0);
        }
        __syncthreads();
        cur ^= 1;
    }

    int rbase = quad * 4;
#pragma unroll
    for (int i = 0; i < 2; i++) {
#pragma unroll
        for (int j = 0; j < 2; j++) {
            int row0 = m0 + wm * 32 + i * 16 + rbase;
            int col = n0 + wn * 32 + j * 16 + cidx;
            if (MODE == 6) {
                int h_ = col >> 6, d = col & 63;
                uint2 t;
                t.x = pack2(acc[i][j][0], acc[i][j][1]);
                t.y = pack2(acc[i][j][2], acc[i][j][3]);
                *(uint2*)&Cq[(size_t)h_ * 131072 + (size_t)d * 2048 + row0] = t;
                continue;
            }
#pragma unroll
            for (int r = 0; r < 4; r++) {
                int row = row0 + r;
                float v = acc[i][j][r];
                size_t idx = (size_t)row * N + col;
                if (MODE == 1) {
                    int h_ = col >> 6, kk = col & 63;
                    float other = __shfl_xor(v, 1);
                    float p = (float)(kk >> 1);
                    float theta = __expf(p * -0.5756462732485114f); // ln(1e4)/16
                    float ang = (float)row * theta;
                    float c, sn; __sincosf(ang, &sn, &c);
                    float outv = (kk & 1) ? (v * c + other * sn) : (v * c - other * sn);
                    Cq[((size_t)h_ * 2048 + row) * 64 + kk] = __float2bfloat16(outv);
                } else if (MODE == 2) {
                    v += resF[idx];
                    ((bf16*)Cdst)[idx] = __float2bfloat16(v);
                } else {
                    v += __bfloat162float(((const bf16*)resv)[idx]);
                    ((float*)Cv)[idx] = v;
                }
            }
        }
    }
}

// ---------------------------------------------------------------------------
// SwiGLU GEMM (retiled this round): C = silu(A@W1) * (A@W2).
// M=2048, N=2048, K=1024 fixed. Block tile 128x64, BK=64 dbuf.
// 4 waves as 2(wm)x2(wn); wave tile 64x32 (af-reuse 4).
// LDS 64KB = 2buf x [A 16K | B1 8K | B2 8K] -> 2 blocks/CU; grid 512 = 2/CU
// exact (old 64^2 version: 1024 blocks at 3/CU cap -> 768+256 ragged tail).
// Same source-pre-swizzle as mfma_gemm (row&7 == cidx&7 identities hold).
// ---------------------------------------------------------------------------
__global__ __launch_bounds__(256) void swiglu_gemm(
    const bf16* __restrict__ A, const bf16* __restrict__ B1T,
    const bf16* __restrict__ B2T, bf16* __restrict__ C)
{
    const int K = 1024, N = 2048;
    __shared__ bf16 smem[2][16384];    // [buf][A 8192 | B1 4096 | B2 4096 elems]
    int tid = threadIdx.x, lane = tid & 63, w = tid >> 6;
    int wm = w >> 1, wn = w & 1;
    int m0 = blockIdx.y * 128, n0 = blockIdx.x * 64;

    int lrow = lane >> 3;
    int lcb  = (lane & 7) ^ lrow;
    const bf16* Ag  = A   + (size_t)(m0 + w * 8 + lrow) * K + lcb * 8;
    const bf16* B1g = B1T + (size_t)(n0 + w * 8 + lrow) * K + lcb * 8;
    const bf16* B2g = B2T + (size_t)(n0 + w * 8 + lrow) * K + lcb * 8;
    unsigned sbase = (unsigned)__builtin_amdgcn_readfirstlane(w * 8 * 128);
    char* smc = (char*)smem;

    f32x4 acc[4][2], acc2[4][2];
#pragma unroll
    for (int i = 0; i < 4; i++)
#pragma unroll
        for (int j = 0; j < 2; j++) {
            acc[i][j] = (f32x4){0.f, 0.f, 0.f, 0.f};
            acc2[i][j] = (f32x4){0.f, 0.f, 0.f, 0.f};
        }

    int cidx = lane & 15, quad = lane >> 4;

    auto STAGE = [&](int buf, int k0) {
        char* p = smc + (size_t)buf * 32768 + sbase;
#pragma unroll
        for (int n = 0; n < 4; n++)                    // A: 128 rows
            gl_lds16(Ag + (size_t)(n * 32) * K + k0, p + n * 4096);
#pragma unroll
        for (int n = 0; n < 2; n++) {                  // B1, B2: 64 rows each
            gl_lds16(B1g + (size_t)(n * 32) * K + k0, p + 16384 + n * 4096);
            gl_lds16(B2g + (size_t)(n * 32) * K + k0, p + 24576 + n * 4096);
        }
    };

    STAGE(0, 0);
    __syncthreads();
    int cur = 0;
    for (int k0 = 0; k0 < K; k0 += 64) {
        if (k0 + 64 < K) STAGE(cur ^ 1, k0 + 64);
        const bf16* Ab = (const bf16*)(smc + (size_t)cur * 32768);
        const bf16* Bb = Ab + 8192;
        const bf16* B2b = Ab + 12288;
#pragma unroll
        for (int kk = 0; kk < 2; kk++) {
            int pb = (kk * 4 + quad) ^ (cidx & 7);
            bf16x8 af[4], bfr[2], b2f[2];
#pragma unroll
            for (int i = 0; i < 4; i++)
                af[i] = *(const bf16x8*)&Ab[(wm * 64 + i * 16 + cidx) * 64 + pb * 8];
#pragma unroll
            for (int j = 0; j < 2; j++) {
                bfr[j] = *(const bf16x8*)&Bb[(wn * 32 + j * 16 + cidx) * 64 + pb * 8];
                b2f[j] = *(const bf16x8*)&B2b[(wn * 32 + j * 16 + cidx) * 64 + pb * 8];
            }
            __builtin_amdgcn_s_setprio(1);
#pragma unroll
            for (int i = 0; i < 4; i++)
#pragma unroll
                for (int j = 0; j < 2; j++) {
                    acc[i][j] = __builtin_amdgcn_mfma_f32_16x16x32_bf16(af[i], bfr[j], acc[i][j], 0, 0, 0);
                    acc2[i][j] = __builtin_amdgcn_mfma_f32_16x16x32_bf16(af[i], b2f[j], acc2[i][j], 0, 0, 0);
                }
            __builtin_amdgcn_s_setprio(0);
        }
        __syncthreads();
        cur ^= 1;
    }

    int rbase = quad * 4;
#pragma unroll
    for (int i = 0; i < 4; i++) {
#pragma unroll
        for (int j = 0; j < 2; j++) {
#pragma unroll
            for (int r = 0; r < 4; r++) {
                int row = m0 + wm * 64 + i * 16 + rbase + r;
                int col = n0 + wn * 32 + j * 16 + cidx;
                float u = acc[i][j][r];
                float g2 = acc2[i][j][r];
                float sg = 1.f / (1.f + __expf(-u));
                C[(size_t)row * N + col] = __float2bfloat16(u * sg * g2);
            }
        }
    }
}

// ---------------------------------------------------------------------------
// MFMA causal flash attention, BOTH batches (z = batch). hd=64. QBLK=64,
// KVBLK=64 (proven r9/r11 kernel, unchanged).
// ---------------------------------------------------------------------------
__global__ __launch_bounds__(256) void attn_kernel(
    const bf16* __restrict__ q0, const bf16* __restrict__ k0,
    const bf16* __restrict__ vt0, bf16* __restrict__ o0,
    const bf16* __restrict__ q1, const bf16* __restrict__ k1,
    const bf16* __restrict__ vt1, bf16* __restrict__ o1)
{
    const int S = 2048;
    __shared__ bf16 Ks[64 * 64];
    __shared__ bf16 Vs[64 * 64];
    __shared__ __align__(16) char QPbuf[64 * 72 * 2];

    int zb = blockIdx.z;
    const bf16* q = zb ? q1 : q0;
    const bf16* k = zb ? k1 : k0;
    const bf16* vt = zb ? vt1 : vt0;
    bf16* o = zb ? o1 : o0;

    int h = blockIdx.y;
    int qt = (h & 8) ? (int)blockIdx.x : 31 - (int)blockIdx.x;
    int tid = threadIdx.x, lane = tid & 63, w = tid >> 6;
    int quad = lane >> 4, cidx = lane & 15;
    int m0 = qt * 64;

    const bf16* qb = q + ((size_t)h * S + m0) * 64;
    const bf16* kb = k + (size_t)h * S * 64;
    const bf16* vtb = vt + (size_t)h * 64 * S;

    int srow = tid >> 2;
    int sg = (tid & 3) * 16;

    bf16 (*Qs)[72] = (bf16 (*)[72])QPbuf;
    {
        const uint4* src = (const uint4*)(qb + (size_t)srow * 64 + sg);
        uint4 u0 = src[0], u1 = src[1];
        float f[16]; unpack8(u0, f); unpack8(u1, f + 8);
#pragma unroll
        for (int i = 0; i < 16; i++) f[i] *= 0.125f * 1.44269504f;
        *(uint4*)&Qs[srow][sg] = packbf8(f);
        *(uint4*)&Qs[srow][sg + 8] = packbf8(f + 8);
    }
    bf16x8 bQ0 = *(const bf16x8*)&Qs[w * 16 + cidx][quad * 8];
    bf16x8 bQ1 = *(const bf16x8*)&Qs[w * 16 + cidx][32 + quad * 8];

    unsigned* Pst = (unsigned*)QPbuf + w * 576;

    int cb0 = (tid & 3) * 2;
    int sw0 = ((cb0)     ^ (srow & 7)) * 8;
    int sw1 = ((cb0 + 1) ^ (srow & 7)) * 8;
    int pb0 = ((quad)     ^ (cidx & 7)) * 8;
    int pb1 = ((4 + quad) ^ (cidx & 7)) * 8;

    float m_i = -INFINITY, l_i = 0.f;
    f32x4 Oc[4];
#pragma unroll
    for (int i = 0; i < 4; i++) Oc[i] = (f32x4){0.f, 0.f, 0.f, 0.f};

    uint4 ka0, ka1, va0, va1;
    {
        const uint4* ksrc = (const uint4*)(kb + (size_t)srow * 64 + sg);
        ka0 = ksrc[0]; ka1 = ksrc[1];
        const uint4* vsrc = (const uint4*)(vtb + (size_t)srow * S + sg);
        va0 = vsrc[0]; va1 = vsrc[1];
    }

    for (int kt = 0; kt <= qt; kt++) {
        __syncthreads();
        *(uint4*)&Ks[srow * 64 + sw0] = ka0;
        *(uint4*)&Ks[srow * 64 + sw1] = ka1;
        *(uint4*)&Vs[srow * 64 + sw0] = va0;
        *(uint4*)&Vs[srow * 64 + sw1] = va1;
        __syncthreads();
        if (kt < qt) {
            const uint4* kn = (const uint4*)(kb + (size_t)((kt + 1) * 64 + srow) * 64 + sg);
            ka0 = kn[0]; ka1 = kn[1];
            const uint4* vn = (const uint4*)(vtb + (size_t)srow * S + (kt + 1) * 64 + sg);
            va0 = vn[0]; va1 = vn[1];
        }

        f32x4 sc[4];
#pragma unroll
        for (int i = 0; i < 4; i++) {
            bf16x8 aK0 = *(const bf16x8*)&Ks[(i * 16 + cidx) * 64 + pb0];
            bf16x8 aK1 = *(const bf16x8*)&Ks[(i * 16 + cidx) * 64 + pb1];
            f32x4 z = (f32x4){0.f, 0.f, 0.f, 0.f};
            __builtin_amdgcn_s_setprio(1);
            z = __builtin_amdgcn_mfma_f32_16x16x32_bf16(aK0, bQ0, z, 0, 0, 0);
            z = __builtin_amdgcn_mfma_f32_16x16x32_bf16(aK1, bQ1, z, 0, 0, 0);
            __builtin_amdgcn_s_setprio(0);
            sc[i] = z;
        }

        if (kt == qt) {
#pragma unroll
            for (int i = 0; i < 4; i++)
#pragma unroll
                for (int r = 0; r < 4; r++)
                    if (i * 16 + quad * 4 + r > w * 16 + cidx) sc[i][r] = -INFINITY;
        }

        float l0 = fmaxf(fmaxf(sc[0][0], sc[0][1]), fmaxf(sc[0][2], sc[0][3]));
        float l1 = fmaxf(fmaxf(sc[1][0], sc[1][1]), fmaxf(sc[1][2], sc[1][3]));
        float l2 = fmaxf(fmaxf(sc[2][0], sc[2][1]), fmaxf(sc[2][2], sc[2][3]));
        float l3 = fmaxf(fmaxf(sc[3][0], sc[3][1]), fmaxf(sc[3][2], sc[3][3]));
        float lmax = fmaxf(fmaxf(l0, l1), fmaxf(l2, l3));

        if (!__all(lmax <= m_i + 8.f)) {
            float pmax = fmaxf(lmax, __shfl_xor(lmax, 16));
            pmax = fmaxf(pmax, __shfl_xor(pmax, 32));
            float mnew = fmaxf(m_i, pmax);
            float alpha = __builtin_amdgcn_exp2f(m_i - mnew);
            l_i *= alpha;
#pragma unroll
            for (int i = 0; i < 4; i++) {
                Oc[i][0] *= alpha; Oc[i][1] *= alpha;
                Oc[i][2] *= alpha; Oc[i][3] *= alpha;
            }
            m_i = mnew;
        }

        float rs = 0.f;
#pragma unroll
        for (int i = 0; i < 4; i++)
#pragma unroll
            for (int r = 0; r < 4; r++) {
                sc[i][r] = __builtin_amdgcn_exp2f(sc[i][r] - m_i);
                rs += sc[i][r];
            }
        l_i += rs;

#pragma unroll
        for (int i = 0; i < 4; i++) {
            uint2 t;
            t.x = pack2(sc[i][0], sc[i][1]);
            t.y = pack2(sc[i][2], sc[i][3]);
            *(uint2*)&Pst[cidx * 36 + 8 * i + 2 * quad] = t;
        }
        bf16x8 bP0 = *(const bf16x8*)&Pst[cidx * 36 + 4 * quad];
        bf16x8 bP1 = *(const bf16x8*)&Pst[cidx * 36 + 16 + 4 * quad];

#pragma unroll
        for (int i = 0; i < 4; i++) {
            bf16x8 aV0 = *(const bf16x8*)&Vs[(i * 16 + cidx) * 64 + pb0];
            bf16x8 aV1 = *(const bf16x8*)&Vs[(i * 16 + cidx) * 64 + pb1];
            __builtin_amdgcn_s_setprio(1);
            Oc[i] = __builtin_amdgcn_mfma_f32_16x16x32_bf16(aV0, bP0, Oc[i], 0, 0, 0);
            Oc[i] = __builtin_amdgcn_mfma_f32_16x16x32_bf16(aV1, bP1, Oc[i], 0, 0, 0);
            __builtin_amdgcn_s_setprio(0);
        }
    }

    float lr = l_i;
    lr += __shfl_xor(lr, 16);
    lr += __shfl_xor(lr, 32);
    float inv = 1.f / lr;
#pragma unroll
    for (int i = 0; i < 4; i++) {
        uint2 t;
        t.x = pack2(Oc[i][0] * inv, Oc[i][1] * inv);
        t.y = pack2(Oc[i][2] * inv, Oc[i][3] * inv);
        *(uint2*)&Pst[cidx * 36 + 8 * i + 2 * quad] = t;
    }
    int r2 = lane >> 2, g2 = (lane & 3) * 8;
    uint4 o0v = *(const uint4*)&Pst[r2 * 36 + g2];
    uint4 o1v = *(const uint4*)&Pst[r2 * 36 + g2 + 4];
    bf16* orow = o + (size_t)(m0 + w * 16 + r2) * 1024 + h * 64;
    *(uint4*)(orow + g2 * 2) = o0v;
    *(uint4*)(orow + g2 * 2 + 8) = o1v;
}

// ---------------------------------------------------------------------------
extern "C" void kernel_launch(void* const* d_in, const int* in_sizes, int n_in,
                              void* d_out, int out_size, void* d_ws, size_t ws_size,
                              hipStream_t stream)
{
    const int S = 2048;

    const float* x    = (const float*)d_in[0];
    const float* ln1g = (const float*)d_in[1];
    const float* ln1b = (const float*)d_in[2];
    const float* Wq   = (const float*)d_in[3];
    const float* Wk   = (const float*)d_in[4];
    const float* Wv   = (const float*)d_in[5];
    const float* Wo   = (const float*)d_in[6];
    const float* ln2g = (const float*)d_in[7];
    const float* ln2b = (const float*)d_in[8];
    const float* W1   = (const float*)d_in[9];
    const float* W2   = (const float*)d_in[10];
    const float* W3   = (const float*)d_in[11];
    float* out = (float*)d_out;

    const size_t M2 = 1u << 21;        // 2M bf16 elems (one 4MB slot)
    bf16* r0 = (bf16*)d_ws;
    bf16* r1 = r0 + M2;
    bf16* r2 = r1 + M2;
    bf16* r3 = r2 + M2;
    bf16* pb0 = (bf16*)out;
    bf16* pb1 = pb0 + 2 * M2;
    float* out0 = out;
    float* out1 = out + (1u << 21);

    // 1. LN1 both -> r0,r1; WqT/WkT/WvT -> pb0[0:3M elems)
    prep1_kernel<<<7168, 256, 0, stream>>>(x, ln1g, ln1b, r0, r1,
                                           Wq, Wk, Wv, pb0);

    // 2. mode6F: vt0 -> P1a(pb1), vt1 -> P1b  (WvT at pb0+M2)
    mfma_gemm<6><<<dim3(16, 32, 2), 256, 0, stream>>>(
        r0, pb0 + M2, pb1, nullptr, r1, pb1 + M2, S, 1024, 1024);

    // 3. QK(b0): q0 -> r2, k0 -> r3 (RoPE)
    mfma_gemm<1><<<dim3(16, 32, 2), 256, 0, stream>>>(
        r0, pb0, r2, nullptr, nullptr, r3, S, 1024, 1024);

    // 4. QK(b1): q1 -> r0 (h0 dead), k1 -> pb0+M2 (WvT dead)
    mfma_gemm<1><<<dim3(16, 32, 2), 256, 0, stream>>>(
        r1, pb0, r0, nullptr, nullptr, pb0 + M2, S, 1024, 1024);

    // 5. attnF: ao0 -> r1 (h1 dead), ao1 -> pb0 (WqT/WkT dead)
    attn_kernel<<<dim3(32, 16, 2), 256, 0, stream>>>(
        r2, r3, pb1, r1, r0, pb0 + M2, pb1 + M2, pb0);

    // 6a. WoT -> r2 (q0 dead)
    tconv_wo_kernel<<<dim3(2, 32, 16), 256, 0, stream>>>(Wo, r2);

    // 6b. mode2F: x2_0 = x0 + ao0@Wo -> r3 (k0 dead); x2_1 -> r0 (q1 dead)
    mfma_gemm<2><<<dim3(16, 32, 2), 256, 0, stream>>>(
        r1, r2, r3, x, pb0, r0, S, 1024, 1024);

    // 7a. prep2(b0)+W3T: h2_0 -> P1a (vt0 dead); W12T -> pb0 (ao1/k1 dead);
    //     W3T -> P1b (vt1 dead)
    prep2_kernel<<<8192, 256, 0, stream>>>(r3, ln2g, ln2b, pb1, W1, W2, pb0,
                                           W3, pb1 + M2);

    // 7b. swiglu(b0): sb0 -> r1..r2 (ao0, WoT dead)
    swiglu_gemm<<<dim3(32, 16), 256, 0, stream>>>(pb1, pb0, pb0 + M2, r1);

    // 7d. out0 = x2_0 + sb0@W3 -> pb0 fp32 (W12T dead)
    mfma_gemm<4><<<dim3(16, 32, 1), 256, 0, stream>>>(
        r1, pb1 + M2, out0, r3, nullptr, nullptr, S, 1024, 2048);

    // 8a. prep2(b1): x2_1=r0 -> h2_1 -> r3 (x2_0 dead); W12T -> pb1
    prep2_kernel<<<6144, 256, 0, stream>>>(r0, ln2g, ln2b, r3, W1, W2, pb1,
                                           nullptr, nullptr);

    // 8b. swiglu(b1): sb1 -> r1..r2 (sb0 dead)
    swiglu_gemm<<<dim3(32, 16), 256, 0, stream>>>(r3, pb1, pb1 + M2, r1);

    // 8c. W3T -> r3 (h2_1 dead)
    tconv_kernel<<<dim3(32, 64), 256, 0, stream>>>(W3, r3, 2048, 1024);

    // 8d. out1 = x2_1 + sb1@W3 -> pb1 fp32 (W12T dead)
    mfma_gemm<4><<<dim3(16, 32, 1), 256, 0, stream>>>(
        r1, r3, out1, r0, nullptr, nullptr, S, 1024, 2048);
}